// Round 1
// baseline (716.478 us; speedup 1.0000x reference)
//
#include <hip/hip_runtime.h>
#include <cstddef>

#define CCH 768
#define NTOK 8192

__device__ __forceinline__ float gelu_tanh(float x) {
    // JAX default gelu (approximate=True): 0.5*x*(1+tanh(sqrt(2/pi)*(x+0.044715x^3)))
    float u = 0.7978845608028654f * (x + 0.044715f * x * x * x);
    float e = __expf(2.0f * u);
    float t = 1.0f - 2.0f / (e + 1.0f);
    return 0.5f * x * (1.0f + t);
}

// BCHW (8,768,32,32) -> token-major [8192][768]
__global__ __launch_bounds__(256) void k_transpose(const float* __restrict__ src,
                                                   float* __restrict__ Xg) {
    __shared__ float tile[32][33];
    int b = blockIdx.z;
    int c0 = blockIdx.y * 32, hw0 = blockIdx.x * 32;
    int tx = threadIdx.x, ty = threadIdx.y;
    const float* s = src + (size_t)b * CCH * 1024;
#pragma unroll
    for (int i = 0; i < 4; ++i) {
        int c = c0 + ty + 8 * i;
        tile[ty + 8 * i][tx] = s[(size_t)c * 1024 + hw0 + tx];
    }
    __syncthreads();
#pragma unroll
    for (int i = 0; i < 4; ++i) {
        int r = ty + 8 * i;
        int n = b * 1024 + hw0 + r;
        Xg[(size_t)n * CCH + c0 + tx] = tile[tx][r];
    }
}

// 64x64 tile GEMM core: acc[4][4] += A[64xK] * W[Kx64]
// arow: pre-offset A row pointer for this thread's loader lane (advances by k0)
// wrow: pre-offset W pointer (advances by k0*CCH)
__device__ __forceinline__ void gemm64x64(const float* arow, const float* wrow,
                                          float acc[4][4], float* As, float* Ws,
                                          int tn, int tc, int ltok, int lkq,
                                          int lk, int lcq) {
    for (int k0 = 0; k0 < CCH; k0 += 16) {
        float4 av = *(const float4*)(arow + k0);
        As[(lkq * 4 + 0) * 68 + ltok] = av.x;
        As[(lkq * 4 + 1) * 68 + ltok] = av.y;
        As[(lkq * 4 + 2) * 68 + ltok] = av.z;
        As[(lkq * 4 + 3) * 68 + ltok] = av.w;
        *(float4*)(Ws + lk * 68 + lcq * 4) = *(const float4*)(wrow + (size_t)k0 * CCH);
        __syncthreads();
#pragma unroll
        for (int k = 0; k < 16; ++k) {
            float4 a4 = *(const float4*)(As + k * 68 + tn * 4);
            float4 w4 = *(const float4*)(Ws + k * 68 + tc * 4);
            float aa[4] = {a4.x, a4.y, a4.z, a4.w};
            float ww[4] = {w4.x, w4.y, w4.z, w4.w};
#pragma unroll
            for (int i = 0; i < 4; ++i)
#pragma unroll
                for (int j = 0; j < 4; ++j)
                    acc[i][j] = fmaf(aa[i], ww[j], acc[i][j]);
        }
        __syncthreads();
    }
}

// G = gelu(Xg @ W1 + b1)   [8192x768]
__global__ __launch_bounds__(256) void k_gate1(const float* __restrict__ Xg,
                                               const float* __restrict__ W,
                                               const float* __restrict__ bias,
                                               float* __restrict__ G) {
    __shared__ float As[16 * 68];
    __shared__ float Ws[16 * 68];
    int t = threadIdx.x;
    int tn = t & 15, tc = t >> 4;
    int ltok = t >> 2, lkq = t & 3;
    int lk = t >> 4, lcq = t & 15;
    int n0 = blockIdx.y * 64, c0 = blockIdx.x * 64;
    const float* arow = Xg + (size_t)(n0 + ltok) * CCH + lkq * 4;
    const float* wrow = W + (size_t)lk * CCH + c0 + lcq * 4;
    float acc[4][4] = {};
    gemm64x64(arow, wrow, acc, As, Ws, tn, tc, ltok, lkq, lk, lcq);
    float4 bv = *(const float4*)(bias + c0 + tc * 4);
    float bb[4] = {bv.x, bv.y, bv.z, bv.w};
#pragma unroll
    for (int i = 0; i < 4; ++i) {
        int n = n0 + tn * 4 + i;
        float4 o;
        o.x = gelu_tanh(acc[i][0] + bb[0]);
        o.y = gelu_tanh(acc[i][1] + bb[1]);
        o.z = gelu_tanh(acc[i][2] + bb[2]);
        o.w = gelu_tanh(acc[i][3] + bb[3]);
        *(float4*)(G + (size_t)n * CCH + c0 + tc * 4) = o;
    }
}

// logits = G @ W2 + b2 -> softmax -> top1 idx + gate value. One wave per token.
__global__ __launch_bounds__(256) void k_gate2(const float* __restrict__ G,
                                               const float* __restrict__ W2,
                                               const float* __restrict__ b2,
                                               int* __restrict__ idx,
                                               float* __restrict__ gval) {
    int t = threadIdx.x;
    int lane = t & 63, wid = t >> 6;
    int n = blockIdx.x * 4 + wid;
    const float* gr = G + (size_t)n * CCH;
    float a0 = 0.f, a1 = 0.f, a2 = 0.f, a3 = 0.f;
#pragma unroll
    for (int i = 0; i < 12; ++i) {
        int c = lane + 64 * i;
        float g = gr[c];
        float4 w = *(const float4*)(W2 + c * 4);
        a0 = fmaf(g, w.x, a0);
        a1 = fmaf(g, w.y, a1);
        a2 = fmaf(g, w.z, a2);
        a3 = fmaf(g, w.w, a3);
    }
#pragma unroll
    for (int off = 32; off > 0; off >>= 1) {
        a0 += __shfl_xor(a0, off);
        a1 += __shfl_xor(a1, off);
        a2 += __shfl_xor(a2, off);
        a3 += __shfl_xor(a3, off);
    }
    if (lane == 0) {
        float l0 = a0 + b2[0], l1 = a1 + b2[1], l2 = a2 + b2[2], l3 = a3 + b2[3];
        int e = 0;
        float m = l0;
        if (l1 > m) { m = l1; e = 1; }
        if (l2 > m) { m = l2; e = 2; }
        if (l3 > m) { m = l3; e = 3; }
        float s = __expf(l0 - m) + __expf(l1 - m) + __expf(l2 - m) + __expf(l3 - m);
        idx[n] = e;
        gval[n] = 1.0f / s;
    }
}

__global__ void k_zero(int* __restrict__ counts) {
    if (threadIdx.x < 16) counts[threadIdx.x] = 0;
}

__global__ __launch_bounds__(256) void k_count(const int* __restrict__ idx,
                                               int* __restrict__ counts) {
    int n = blockIdx.x * 256 + threadIdx.x;
    int e = idx[n];
#pragma unroll
    for (int ee = 0; ee < 4; ++ee)
        if (e == ee) atomicAdd(counts + ee, 1);
}

__global__ void k_prefix(const int* __restrict__ counts, int* __restrict__ offs,
                         int* __restrict__ cursors) {
    if (threadIdx.x == 0 && blockIdx.x == 0) {
        int o = 0;
        for (int e = 0; e < 4; ++e) {
            offs[e] = o;
            cursors[e] = o;
            o += counts[e];
        }
        offs[4] = o;
    }
}

__global__ __launch_bounds__(256) void k_scatter(const int* __restrict__ idx,
                                                 int* __restrict__ cursors,
                                                 int* __restrict__ perm) {
    int n = blockIdx.x * 256 + threadIdx.x;
    int e = idx[n];
#pragma unroll
    for (int ee = 0; ee < 4; ++ee)
        if (e == ee) {
            int pos = atomicAdd(cursors + ee, 1);
            perm[pos] = n;
        }
}

// H[p] = gelu(Xg[perm[p]] @ exp_w1[e] + exp_b1[e]), rows in perm order
__global__ __launch_bounds__(256) void k_exp1(const float* __restrict__ Xg,
                                              const float* __restrict__ EW1,
                                              const float* __restrict__ EB1,
                                              const int* __restrict__ perm,
                                              const int* __restrict__ counts,
                                              const int* __restrict__ offs,
                                              float* __restrict__ H) {
    __shared__ float As[16 * 68];
    __shared__ float Ws[16 * 68];
    int slot = blockIdx.y;
    int e = slot >> 7;
    int ts = slot & 127;
    int cnt = counts[e];
    if (ts * 64 >= cnt) return;
    int ofs = offs[e];
    int c0 = blockIdx.x * 64;
    const float* W = EW1 + (size_t)e * CCH * CCH;
    int t = threadIdx.x;
    int tn = t & 15, tc = t >> 4;
    int ltok = t >> 2, lkq = t & 3;
    int lk = t >> 4, lcq = t & 15;
    int pl = ts * 64 + ltok;
    int pc = pl < cnt ? pl : cnt - 1;
    int nrow = perm[ofs + pc];
    const float* arow = Xg + (size_t)nrow * CCH + lkq * 4;
    const float* wrow = W + (size_t)lk * CCH + c0 + lcq * 4;
    float acc[4][4] = {};
    gemm64x64(arow, wrow, acc, As, Ws, tn, tc, ltok, lkq, lk, lcq);
    float4 bv = *(const float4*)(EB1 + (size_t)e * CCH + c0 + tc * 4);
    float bb[4] = {bv.x, bv.y, bv.z, bv.w};
#pragma unroll
    for (int i = 0; i < 4; ++i) {
        int plo = ts * 64 + tn * 4 + i;
        if (plo < cnt) {
            float4 o;
            o.x = gelu_tanh(acc[i][0] + bb[0]);
            o.y = gelu_tanh(acc[i][1] + bb[1]);
            o.z = gelu_tanh(acc[i][2] + bb[2]);
            o.w = gelu_tanh(acc[i][3] + bb[3]);
            *(float4*)(H + (size_t)(ofs + plo) * CCH + c0 + tc * 4) = o;
        }
    }
}

// out32 = (H @ exp_w2[e] + exp_b2[e]) * gval + x, scattered back to BCHW
__global__ __launch_bounds__(256) void k_exp2(const float* __restrict__ H,
                                              const float* __restrict__ EW2,
                                              const float* __restrict__ EB2,
                                              const int* __restrict__ perm,
                                              const int* __restrict__ counts,
                                              const int* __restrict__ offs,
                                              const float* __restrict__ gval,
                                              const float* __restrict__ Xg,
                                              float* __restrict__ out32) {
    __shared__ float As[16 * 68];
    __shared__ float Ws[16 * 68];
    int slot = blockIdx.y;
    int e = slot >> 7;
    int ts = slot & 127;
    int cnt = counts[e];
    if (ts * 64 >= cnt) return;
    int ofs = offs[e];
    int c0 = blockIdx.x * 64;
    const float* W = EW2 + (size_t)e * CCH * CCH;
    int t = threadIdx.x;
    int tn = t & 15, tc = t >> 4;
    int ltok = t >> 2, lkq = t & 3;
    int lk = t >> 4, lcq = t & 15;
    int pl = ts * 64 + ltok;
    int pc = pl < cnt ? pl : cnt - 1;
    const float* arow = H + (size_t)(ofs + pc) * CCH + lkq * 4;
    const float* wrow = W + (size_t)lk * CCH + c0 + lcq * 4;
    float acc[4][4] = {};
    gemm64x64(arow, wrow, acc, As, Ws, tn, tc, ltok, lkq, lk, lcq);
    float4 bv = *(const float4*)(EB2 + (size_t)e * CCH + c0 + tc * 4);
    float bb[4] = {bv.x, bv.y, bv.z, bv.w};
#pragma unroll
    for (int i = 0; i < 4; ++i) {
        int plo = ts * 64 + tn * 4 + i;
        if (plo < cnt) {
            int n = perm[ofs + plo];
            float gv = gval[n];
            float4 xv = *(const float4*)(Xg + (size_t)n * CCH + c0 + tc * 4);
            int b = n >> 10, hw = n & 1023;
            size_t cb = (size_t)(b * CCH + c0 + tc * 4);
            out32[((cb + 0) << 10) | (size_t)hw] = fmaf(acc[i][0] + bb[0], gv, xv.x);
            out32[((cb + 1) << 10) | (size_t)hw] = fmaf(acc[i][1] + bb[1], gv, xv.y);
            out32[((cb + 2) << 10) | (size_t)hw] = fmaf(acc[i][2] + bb[2], gv, xv.z);
            out32[((cb + 3) << 10) | (size_t)hw] = fmaf(acc[i][3] + bb[3], gv, xv.w);
        }
    }
}

extern "C" void kernel_launch(void* const* d_in, const int* in_sizes, int n_in,
                              void* d_out, int out_size, void* d_ws, size_t ws_size,
                              hipStream_t stream) {
    const float* s4  = (const float*)d_in[0];
    const float* s8  = (const float*)d_in[1];
    const float* s16 = (const float*)d_in[2];
    const float* s32 = (const float*)d_in[3];
    const float* gw1 = (const float*)d_in[4];
    const float* gb1 = (const float*)d_in[5];
    const float* gw2 = (const float*)d_in[6];
    const float* gb2 = (const float*)d_in[7];
    const float* ew1 = (const float*)d_in[8];
    const float* eb1 = (const float*)d_in[9];
    const float* ew2 = (const float*)d_in[10];
    const float* eb2 = (const float*)d_in[11];

    float* base = (float*)d_out;
    // scratch lives in the s4 region of d_out; it is overwritten by the final
    // s4 memcpy which runs after all compute on the same stream.
    float* Xg   = base;                  // 8192*768
    float* G    = base + 6291456;        // 8192*768
    float* Hh   = base + 12582912;       // 8192*768
    int*   iaux = (int*)(base + 18874368);
    int*   idx     = iaux;               // 8192
    int*   perm    = iaux + 8192;        // 8192
    int*   counts  = iaux + 16384;       // 4
    int*   offs    = iaux + 16392;       // 5
    int*   cursors = iaux + 16400;       // 4
    float* gval = base + 18874368 + 20480;  // 8192
    float* out32 = base + 88080384;

    k_transpose<<<dim3(32, 24, 8), dim3(32, 8), 0, stream>>>(s32, Xg);
    k_gate1<<<dim3(12, 128), 256, 0, stream>>>(Xg, gw1, gb1, G);
    k_gate2<<<2048, 256, 0, stream>>>(G, gw2, gb2, idx, gval);
    k_zero<<<1, 64, 0, stream>>>(counts);
    k_count<<<32, 256, 0, stream>>>(idx, counts);
    k_prefix<<<1, 64, 0, stream>>>(counts, offs, cursors);
    k_scatter<<<32, 256, 0, stream>>>(idx, cursors, perm);
    k_exp1<<<dim3(12, 512), 256, 0, stream>>>(Xg, ew1, eb1, perm, counts, offs, Hh);
    k_exp2<<<dim3(12, 512), 256, 0, stream>>>(Hh, ew2, eb2, perm, counts, offs, gval, Xg, out32);

    hipMemcpyAsync(base,            s4,  50331648ull * 4, hipMemcpyDeviceToDevice, stream);
    hipMemcpyAsync(base + 50331648, s8,  25165824ull * 4, hipMemcpyDeviceToDevice, stream);
    hipMemcpyAsync(base + 75497472, s16, 12582912ull * 4, hipMemcpyDeviceToDevice, stream);
}

// Round 2
// 533.042 us; speedup vs baseline: 1.3441x; 1.3441x over previous
//
#include <hip/hip_runtime.h>
#include <cstddef>

#define CCH 768
#define NTOK 8192

typedef __attribute__((ext_vector_type(8))) short short8v;
typedef __attribute__((ext_vector_type(4))) float f32x4;

__device__ __forceinline__ float gelu_tanh(float x) {
    // JAX default gelu (approximate=True)
    float u = 0.7978845608028654f * (x + 0.044715f * x * x * x);
    float e = __expf(2.0f * u);
    float t = 1.0f - 2.0f / (e + 1.0f);
    return 0.5f * x * (1.0f + t);
}

__device__ __forceinline__ short f2b(float f) {
    unsigned u = __float_as_uint(f);
    unsigned r = (u + 0x7FFFu + ((u >> 16) & 1u)) >> 16;
    return (short)r;
}

// BCHW (8,768,32,32) -> token-major [8192][768] f32 Xg + bf16 Xb
__global__ __launch_bounds__(256) void k_transpose(const float* __restrict__ src,
                                                   float* __restrict__ Xg,
                                                   short* __restrict__ Xb) {
    __shared__ float tile[32][33];
    int b = blockIdx.z;
    int c0 = blockIdx.y * 32, hw0 = blockIdx.x * 32;
    int tx = threadIdx.x, ty = threadIdx.y;
    const float* s = src + (size_t)b * CCH * 1024;
#pragma unroll
    for (int i = 0; i < 4; ++i) {
        int c = c0 + ty + 8 * i;
        tile[ty + 8 * i][tx] = s[(size_t)c * 1024 + hw0 + tx];
    }
    __syncthreads();
#pragma unroll
    for (int i = 0; i < 4; ++i) {
        int r = ty + 8 * i;
        int n = b * 1024 + hw0 + r;
        float v = tile[tx][r];
        Xg[(size_t)n * CCH + c0 + tx] = v;
        Xb[(size_t)n * CCH + c0 + tx] = f2b(v);
    }
}

// expert weights [4][768][768] f32 (cin-major) -> bf16 transposed [4][cout][cin]
__global__ __launch_bounds__(256) void k_cvtw(const float* __restrict__ ew1,
                                              const float* __restrict__ ew2,
                                              short* __restrict__ W1T,
                                              short* __restrict__ W2T) {
    __shared__ float tile[32][33];
    int z = blockIdx.z;
    const float* src = (z < 4 ? ew1 : ew2) + (size_t)(z & 3) * CCH * CCH;
    short* dst = (z < 4 ? W1T : W2T) + (size_t)(z & 3) * CCH * CCH;
    int ci0 = blockIdx.x * 32, co0 = blockIdx.y * 32;
    int tx = threadIdx.x, ty = threadIdx.y;
#pragma unroll
    for (int i = 0; i < 4; ++i)
        tile[ty + 8 * i][tx] = src[(size_t)(ci0 + ty + 8 * i) * CCH + co0 + tx];
    __syncthreads();
#pragma unroll
    for (int i = 0; i < 4; ++i) {
        int co = co0 + ty + 8 * i;
        dst[(size_t)co * CCH + ci0 + tx] = f2b(tile[tx][ty + 8 * i]);
    }
}

// f32 64x64 tile GEMM core (gate layer 1 keeps full precision for routing)
__device__ __forceinline__ void gemm64x64(const float* arow, const float* wrow,
                                          float acc[4][4], float* As, float* Ws,
                                          int tn, int tc, int ltok, int lkq,
                                          int lk, int lcq) {
    for (int k0 = 0; k0 < CCH; k0 += 16) {
        float4 av = *(const float4*)(arow + k0);
        As[(lkq * 4 + 0) * 68 + ltok] = av.x;
        As[(lkq * 4 + 1) * 68 + ltok] = av.y;
        As[(lkq * 4 + 2) * 68 + ltok] = av.z;
        As[(lkq * 4 + 3) * 68 + ltok] = av.w;
        *(float4*)(Ws + lk * 68 + lcq * 4) = *(const float4*)(wrow + (size_t)k0 * CCH);
        __syncthreads();
#pragma unroll
        for (int k = 0; k < 16; ++k) {
            float4 a4 = *(const float4*)(As + k * 68 + tn * 4);
            float4 w4 = *(const float4*)(Ws + k * 68 + tc * 4);
            float aa[4] = {a4.x, a4.y, a4.z, a4.w};
            float ww[4] = {w4.x, w4.y, w4.z, w4.w};
#pragma unroll
            for (int i = 0; i < 4; ++i)
#pragma unroll
                for (int j = 0; j < 4; ++j)
                    acc[i][j] = fmaf(aa[i], ww[j], acc[i][j]);
        }
        __syncthreads();
    }
}

// G = gelu(Xg @ W1 + b1)   [8192x768] f32
__global__ __launch_bounds__(256) void k_gate1(const float* __restrict__ Xg,
                                               const float* __restrict__ W,
                                               const float* __restrict__ bias,
                                               float* __restrict__ G) {
    __shared__ float As[16 * 68];
    __shared__ float Ws[16 * 68];
    int t = threadIdx.x;
    int tn = t & 15, tc = t >> 4;
    int ltok = t >> 2, lkq = t & 3;
    int lk = t >> 4, lcq = t & 15;
    int n0 = blockIdx.y * 64, c0 = blockIdx.x * 64;
    const float* arow = Xg + (size_t)(n0 + ltok) * CCH + lkq * 4;
    const float* wrow = W + (size_t)lk * CCH + c0 + lcq * 4;
    float acc[4][4] = {};
    gemm64x64(arow, wrow, acc, As, Ws, tn, tc, ltok, lkq, lk, lcq);
    float4 bv = *(const float4*)(bias + c0 + tc * 4);
    float bb[4] = {bv.x, bv.y, bv.z, bv.w};
#pragma unroll
    for (int i = 0; i < 4; ++i) {
        int n = n0 + tn * 4 + i;
        float4 o;
        o.x = gelu_tanh(acc[i][0] + bb[0]);
        o.y = gelu_tanh(acc[i][1] + bb[1]);
        o.z = gelu_tanh(acc[i][2] + bb[2]);
        o.w = gelu_tanh(acc[i][3] + bb[3]);
        *(float4*)(G + (size_t)n * CCH + c0 + tc * 4) = o;
    }
}

// logits = G @ W2 + b2 -> softmax -> top1 idx + gate value. One wave per token.
__global__ __launch_bounds__(256) void k_gate2(const float* __restrict__ G,
                                               const float* __restrict__ W2,
                                               const float* __restrict__ b2,
                                               int* __restrict__ idx,
                                               float* __restrict__ gval) {
    int t = threadIdx.x;
    int lane = t & 63, wid = t >> 6;
    int n = blockIdx.x * 4 + wid;
    const float* gr = G + (size_t)n * CCH;
    float a0 = 0.f, a1 = 0.f, a2 = 0.f, a3 = 0.f;
#pragma unroll
    for (int i = 0; i < 12; ++i) {
        int c = lane + 64 * i;
        float g = gr[c];
        float4 w = *(const float4*)(W2 + c * 4);
        a0 = fmaf(g, w.x, a0);
        a1 = fmaf(g, w.y, a1);
        a2 = fmaf(g, w.z, a2);
        a3 = fmaf(g, w.w, a3);
    }
#pragma unroll
    for (int off = 32; off > 0; off >>= 1) {
        a0 += __shfl_xor(a0, off);
        a1 += __shfl_xor(a1, off);
        a2 += __shfl_xor(a2, off);
        a3 += __shfl_xor(a3, off);
    }
    if (lane == 0) {
        float l0 = a0 + b2[0], l1 = a1 + b2[1], l2 = a2 + b2[2], l3 = a3 + b2[3];
        int e = 0;
        float m = l0;
        if (l1 > m) { m = l1; e = 1; }
        if (l2 > m) { m = l2; e = 2; }
        if (l3 > m) { m = l3; e = 3; }
        float s = __expf(l0 - m) + __expf(l1 - m) + __expf(l2 - m) + __expf(l3 - m);
        idx[n] = e;
        gval[n] = 1.0f / s;
    }
}

__global__ void k_zero(int* __restrict__ counts) {
    if (threadIdx.x < 16) counts[threadIdx.x] = 0;
}

__global__ __launch_bounds__(256) void k_count(const int* __restrict__ idx,
                                               int* __restrict__ counts) {
    int n = blockIdx.x * 256 + threadIdx.x;
    int e = idx[n];
#pragma unroll
    for (int ee = 0; ee < 4; ++ee)
        if (e == ee) atomicAdd(counts + ee, 1);
}

__global__ void k_prefix(const int* __restrict__ counts, int* __restrict__ offs,
                         int* __restrict__ cursors) {
    if (threadIdx.x == 0 && blockIdx.x == 0) {
        int o = 0;
        for (int e = 0; e < 4; ++e) {
            offs[e] = o;
            cursors[e] = o;
            o += counts[e];
        }
        offs[4] = o;
    }
}

__global__ __launch_bounds__(256) void k_scatter(const int* __restrict__ idx,
                                                 int* __restrict__ cursors,
                                                 int* __restrict__ perm) {
    int n = blockIdx.x * 256 + threadIdx.x;
    int e = idx[n];
#pragma unroll
    for (int ee = 0; ee < 4; ++ee)
        if (e == ee) {
            int pos = atomicAdd(cursors + ee, 1);
            perm[pos] = n;
        }
}

// bf16 MFMA expert layer. Block: 64 tokens x 64 couts, 4 waves (each 16x64).
// LDS is fragment-major: every ds_read/ds_write is a conflict-free b128.
// FIRST: H[ofs+p] = gelu(Xb[perm] @ W1T^T + b1)  (bf16 out, perm-row-order)
// else : out32    = (H @ W2T^T + b2) * gval + Xg (scatter to BCHW)
template <bool FIRST>
__global__ __launch_bounds__(256) void k_expert(const short* __restrict__ Abuf,
                                                const short* __restrict__ WT,
                                                const float* __restrict__ EB,
                                                const int* __restrict__ perm,
                                                const int* __restrict__ counts,
                                                const int* __restrict__ offs,
                                                const float* __restrict__ gval,
                                                const float* __restrict__ Xg,
                                                short* __restrict__ Hh,
                                                float* __restrict__ out32) {
    __shared__ __align__(16) short As[4096];
    __shared__ __align__(16) short Bs[4096];
    int slot = blockIdx.y;
    int e = slot >> 7, ts = slot & 127;
    int cnt = counts[e];
    if (ts * 64 >= cnt) return;
    int ofs = offs[e];
    int c0 = blockIdx.x * 64;
    int t = threadIdx.x;
    int lane = t & 63, w = t >> 6;

    // staging: thread t owns (row sr, 16B chunks sc and sc+4)
    int sr = t >> 2;
    int sc = t & 3;
    int pl = ts * 64 + sr;
    int pc = pl < cnt ? pl : cnt - 1;
    int arow = FIRST ? perm[ofs + pc] : (ofs + pc);
    const short* aptr = Abuf + (size_t)arow * CCH;
    const short* bptr = WT + (size_t)e * CCH * CCH + (size_t)(c0 + sr) * CCH;
    int l_lo = sr & 15, g_hi = sr >> 4;
    int dst0 = ((g_hi * 2 + 0) * 64 + l_lo + 16 * sc) * 8;  // kk=0, k-chunk sc
    int dst1 = ((g_hi * 2 + 1) * 64 + l_lo + 16 * sc) * 8;  // kk=1, k-chunk sc

    f32x4 acc[4] = {};
    for (int k0 = 0; k0 < CCH; k0 += 64) {
        *(short8v*)(As + dst0) = *(const short8v*)(aptr + k0 + sc * 8);
        *(short8v*)(As + dst1) = *(const short8v*)(aptr + k0 + 32 + sc * 8);
        *(short8v*)(Bs + dst0) = *(const short8v*)(bptr + k0 + sc * 8);
        *(short8v*)(Bs + dst1) = *(const short8v*)(bptr + k0 + 32 + sc * 8);
        __syncthreads();
#pragma unroll
        for (int kk = 0; kk < 2; ++kk) {
            short8v a = *(const short8v*)(As + ((w * 2 + kk) * 64 + lane) * 8);
#pragma unroll
            for (int nt = 0; nt < 4; ++nt) {
                short8v b = *(const short8v*)(Bs + ((nt * 2 + kk) * 64 + lane) * 8);
                acc[nt] = __builtin_amdgcn_mfma_f32_16x16x32_bf16(a, b, acc[nt], 0, 0, 0);
            }
        }
        __syncthreads();
    }

    // epilogue: D frag row = 4*(lane>>4)+r (within wave's 16), col = lane&15
#pragma unroll
    for (int nt = 0; nt < 4; ++nt) {
        int col = c0 + nt * 16 + (lane & 15);
        float bias = EB[e * CCH + col];
#pragma unroll
        for (int r = 0; r < 4; ++r) {
            int p = ts * 64 + w * 16 + (lane >> 4) * 4 + r;
            if (p < cnt) {
                float v = acc[nt][r] + bias;
                if (FIRST) {
                    Hh[(size_t)(ofs + p) * CCH + col] = f2b(gelu_tanh(v));
                } else {
                    int n = perm[ofs + p];
                    float gv = gval[n];
                    float x = Xg[(size_t)n * CCH + col];
                    int b = n >> 10, hw = n & 1023;
                    out32[((size_t)(b * CCH + col) << 10) | (size_t)hw] =
                        fmaf(v, gv, x);
                }
            }
        }
    }
}

extern "C" void kernel_launch(void* const* d_in, const int* in_sizes, int n_in,
                              void* d_out, int out_size, void* d_ws, size_t ws_size,
                              hipStream_t stream) {
    const float* s4  = (const float*)d_in[0];
    const float* s8  = (const float*)d_in[1];
    const float* s16 = (const float*)d_in[2];
    const float* s32 = (const float*)d_in[3];
    const float* gw1 = (const float*)d_in[4];
    const float* gb1 = (const float*)d_in[5];
    const float* gw2 = (const float*)d_in[6];
    const float* gb2 = (const float*)d_in[7];
    const float* ew1 = (const float*)d_in[8];
    const float* eb1 = (const float*)d_in[9];
    const float* ew2 = (const float*)d_in[10];
    const float* eb2 = (const float*)d_in[11];

    float* base = (float*)d_out;
    // scratch lives in the s4 region of d_out; the final s4 memcpy (same
    // stream, after all compute) overwrites it. Everything is rewritten
    // every call -> deterministic under graph replay.
    float* Xg  = base;                       // 6291456 f32
    float* G   = base + 6291456;             // 6291456 f32
    short* Xb  = (short*)(base + 12582912);  // 6291456 bf16
    short* Hh  = (short*)(base + 15728640);  // 6291456 bf16
    short* W1T = (short*)(base + 18874368);  // 2359296 bf16
    short* W2T = (short*)(base + 20054016);  // 2359296 bf16
    int* iaux  = (int*)(base + 21233664);
    int* idx     = iaux;            // 8192
    int* perm    = iaux + 8192;     // 8192
    int* counts  = iaux + 16384;    // 4
    int* offs    = iaux + 16400;    // 5
    int* cursors = iaux + 16416;    // 4
    float* gval  = base + 21233664 + 20480;  // 8192
    float* out32 = base + 88080384;

    k_transpose<<<dim3(32, 24, 8), dim3(32, 8), 0, stream>>>(s32, Xg, Xb);
    k_cvtw<<<dim3(24, 24, 8), dim3(32, 8), 0, stream>>>(ew1, ew2, W1T, W2T);
    k_gate1<<<dim3(12, 128), 256, 0, stream>>>(Xg, gw1, gb1, G);
    k_gate2<<<2048, 256, 0, stream>>>(G, gw2, gb2, idx, gval);
    k_zero<<<1, 64, 0, stream>>>(counts);
    k_count<<<32, 256, 0, stream>>>(idx, counts);
    k_prefix<<<1, 64, 0, stream>>>(counts, offs, cursors);
    k_scatter<<<32, 256, 0, stream>>>(idx, cursors, perm);
    k_expert<true><<<dim3(12, 512), 256, 0, stream>>>(Xb, W1T, eb1, perm, counts,
                                                      offs, gval, Xg, Hh, out32);
    k_expert<false><<<dim3(12, 512), 256, 0, stream>>>(Hh, W2T, eb2, perm, counts,
                                                       offs, gval, Xg, Hh, out32);

    hipMemcpyAsync(base,            s4,  50331648ull * 4, hipMemcpyDeviceToDevice, stream);
    hipMemcpyAsync(base + 50331648, s8,  25165824ull * 4, hipMemcpyDeviceToDevice, stream);
    hipMemcpyAsync(base + 75497472, s16, 12582912ull * 4, hipMemcpyDeviceToDevice, stream);
}

// Round 3
// 527.561 us; speedup vs baseline: 1.3581x; 1.0104x over previous
//
#include <hip/hip_runtime.h>
#include <cstddef>

#define CCH 768
#define NTOK 8192

typedef __attribute__((ext_vector_type(8))) short short8v;
typedef __attribute__((ext_vector_type(4))) float f32x4;

// ---- scratch layout in the s4 region of d_out (byte offsets) ----
// long-lived (until exp2 done; restored by final 18MiB memcpy):
//   Hh    @ 0         (12582912 B bf16)
//   W2T   @ 12582912  (4718592 B bf16)
//   idx   @ 17301504, perm @ 17334272, counts @ 17367040,
//   offs  @ 17367104, cursors @ 17367168, gval @ 17367232 (+32768)
// mid-lived (dead once exp1 completes; copied over inside exp2):
//   Xg    @ 18874368  (25165824 B f32)
//   Xb    @ 44040192  (12582912 B bf16)
//   G     @ 56623104  (25165824 B f32)
//   W1T   @ 81788928  (4718592 B bf16)   ends 86507520, pad to 87031808
// early region [87031808, 201326592) of s4 + all s8 + s16: copied inside gate1.
#define MIDB   18874368u
#define EARLYB 87031808u
#define S4B    201326592u
#define S8B    100663296u
#define S16DST 301989888u
#define CHUNK  262144u   // 256 KiB copy chunk: 256 thr x 16 B x 64 iters
#define N_EARLY 1012     // 436 (s4) + 384 (s8) + 192 (s16)
#define N_MID   260      // 65 MiB

__device__ __forceinline__ void copy_chunk_raw(const char* src, char* dst) {
    const uint4* s = (const uint4*)src;
    uint4* d = (uint4*)dst;
    int t = threadIdx.x;
#pragma unroll 8
    for (int it = 0; it < 64; ++it) d[it * 256 + t] = s[it * 256 + t];
}

__device__ __forceinline__ float gelu_tanh(float x) {
    // JAX default gelu (approximate=True)
    float u = 0.7978845608028654f * (x + 0.044715f * x * x * x);
    float e = __expf(2.0f * u);
    float t = 1.0f - 2.0f / (e + 1.0f);
    return 0.5f * x * (1.0f + t);
}

__device__ __forceinline__ short f2b(float f) {
    unsigned u = __float_as_uint(f);
    unsigned r = (u + 0x7FFFu + ((u >> 16) & 1u)) >> 16;
    return (short)r;
}

// BCHW (8,768,32,32) -> token-major [8192][768] f32 Xg + bf16 Xb; zero counts
__global__ __launch_bounds__(256) void k_transpose(const float* __restrict__ src,
                                                   float* __restrict__ Xg,
                                                   short* __restrict__ Xb,
                                                   int* __restrict__ counts) {
    if (blockIdx.x == 0 && blockIdx.y == 0 && blockIdx.z == 0 &&
        threadIdx.y == 0 && threadIdx.x < 16)
        counts[threadIdx.x] = 0;
    __shared__ float tile[32][33];
    int b = blockIdx.z;
    int c0 = blockIdx.y * 32, hw0 = blockIdx.x * 32;
    int tx = threadIdx.x, ty = threadIdx.y;
    const float* s = src + (size_t)b * CCH * 1024;
#pragma unroll
    for (int i = 0; i < 4; ++i) {
        int c = c0 + ty + 8 * i;
        tile[ty + 8 * i][tx] = s[(size_t)c * 1024 + hw0 + tx];
    }
    __syncthreads();
#pragma unroll
    for (int i = 0; i < 4; ++i) {
        int r = ty + 8 * i;
        int n = b * 1024 + hw0 + r;
        float v = tile[tx][r];
        Xg[(size_t)n * CCH + c0 + tx] = v;
        Xb[(size_t)n * CCH + c0 + tx] = f2b(v);
    }
}

// expert weights [4][768][768] f32 (cin-major) -> bf16 transposed [4][cout][cin]
__global__ __launch_bounds__(256) void k_cvtw(const float* __restrict__ ew1,
                                              const float* __restrict__ ew2,
                                              short* __restrict__ W1T,
                                              short* __restrict__ W2T) {
    __shared__ float tile[32][33];
    int z = blockIdx.z;
    const float* src = (z < 4 ? ew1 : ew2) + (size_t)(z & 3) * CCH * CCH;
    short* dst = (z < 4 ? W1T : W2T) + (size_t)(z & 3) * CCH * CCH;
    int ci0 = blockIdx.x * 32, co0 = blockIdx.y * 32;
    int tx = threadIdx.x, ty = threadIdx.y;
#pragma unroll
    for (int i = 0; i < 4; ++i)
        tile[ty + 8 * i][tx] = src[(size_t)(ci0 + ty + 8 * i) * CCH + co0 + tx];
    __syncthreads();
#pragma unroll
    for (int i = 0; i < 4; ++i) {
        int co = co0 + ty + 8 * i;
        dst[(size_t)co * CCH + ci0 + tx] = f2b(tile[tx][ty + 8 * i]);
    }
}

// f32 64x64 tile GEMM core (gate layer 1 keeps full precision for routing)
__device__ __forceinline__ void gemm64x64(const float* arow, const float* wrow,
                                          float acc[4][4], float* As, float* Ws,
                                          int tn, int tc, int ltok, int lkq,
                                          int lk, int lcq) {
    for (int k0 = 0; k0 < CCH; k0 += 16) {
        float4 av = *(const float4*)(arow + k0);
        As[(lkq * 4 + 0) * 68 + ltok] = av.x;
        As[(lkq * 4 + 1) * 68 + ltok] = av.y;
        As[(lkq * 4 + 2) * 68 + ltok] = av.z;
        As[(lkq * 4 + 3) * 68 + ltok] = av.w;
        *(float4*)(Ws + lk * 68 + lcq * 4) = *(const float4*)(wrow + (size_t)k0 * CCH);
        __syncthreads();
#pragma unroll
        for (int k = 0; k < 16; ++k) {
            float4 a4 = *(const float4*)(As + k * 68 + tn * 4);
            float4 w4 = *(const float4*)(Ws + k * 68 + tc * 4);
            float aa[4] = {a4.x, a4.y, a4.z, a4.w};
            float ww[4] = {w4.x, w4.y, w4.z, w4.w};
#pragma unroll
            for (int i = 0; i < 4; ++i)
#pragma unroll
                for (int j = 0; j < 4; ++j)
                    acc[i][j] = fmaf(aa[i], ww[j], acc[i][j]);
        }
        __syncthreads();
    }
}

// G = gelu(Xg @ W1 + b1) [8192x768] f32, PLUS 1012 fused copy-chunk blocks
// covering s4[early region], s8, s16 (VALU-bound GEMM absorbs copy HBM traffic).
__global__ __launch_bounds__(256) void k_gate1(const float* __restrict__ Xg,
                                               const float* __restrict__ W,
                                               const float* __restrict__ bias,
                                               float* __restrict__ G,
                                               const char* __restrict__ s4b,
                                               const char* __restrict__ s8b,
                                               const char* __restrict__ s16b,
                                               char* __restrict__ bb) {
    int bid = blockIdx.x;
    if (bid >= 1536) {
        int i = bid - 1536;
        if (i < 436) {
            size_t off = EARLYB + (size_t)i * CHUNK;
            copy_chunk_raw(s4b + off, bb + off);
        } else if (i < 820) {
            size_t off = (size_t)(i - 436) * CHUNK;
            copy_chunk_raw(s8b + off, bb + S4B + off);
        } else {
            size_t off = (size_t)(i - 820) * CHUNK;
            copy_chunk_raw(s16b + off, bb + S16DST + off);
        }
        return;
    }
    __shared__ float As[16 * 68];
    __shared__ float Ws[16 * 68];
    int t = threadIdx.x;
    int tn = t & 15, tc = t >> 4;
    int ltok = t >> 2, lkq = t & 3;
    int lk = t >> 4, lcq = t & 15;
    int n0 = (bid / 12) * 64, c0 = (bid % 12) * 64;
    const float* arow = Xg + (size_t)(n0 + ltok) * CCH + lkq * 4;
    const float* wrow = W + (size_t)lk * CCH + c0 + lcq * 4;
    float acc[4][4] = {};
    gemm64x64(arow, wrow, acc, As, Ws, tn, tc, ltok, lkq, lk, lcq);
    float4 bv = *(const float4*)(bias + c0 + tc * 4);
    float bb4[4] = {bv.x, bv.y, bv.z, bv.w};
#pragma unroll
    for (int i = 0; i < 4; ++i) {
        int n = n0 + tn * 4 + i;
        float4 o;
        o.x = gelu_tanh(acc[i][0] + bb4[0]);
        o.y = gelu_tanh(acc[i][1] + bb4[1]);
        o.z = gelu_tanh(acc[i][2] + bb4[2]);
        o.w = gelu_tanh(acc[i][3] + bb4[3]);
        *(float4*)(G + (size_t)n * CCH + c0 + tc * 4) = o;
    }
}

// logits = G @ W2 + b2 -> softmax -> top1 idx + gate value. One wave per token.
__global__ __launch_bounds__(256) void k_gate2(const float* __restrict__ G,
                                               const float* __restrict__ W2,
                                               const float* __restrict__ b2,
                                               int* __restrict__ idx,
                                               float* __restrict__ gval) {
    int t = threadIdx.x;
    int lane = t & 63, wid = t >> 6;
    int n = blockIdx.x * 4 + wid;
    const float* gr = G + (size_t)n * CCH;
    float a0 = 0.f, a1 = 0.f, a2 = 0.f, a3 = 0.f;
#pragma unroll
    for (int i = 0; i < 12; ++i) {
        int c = lane + 64 * i;
        float g = gr[c];
        float4 w = *(const float4*)(W2 + c * 4);
        a0 = fmaf(g, w.x, a0);
        a1 = fmaf(g, w.y, a1);
        a2 = fmaf(g, w.z, a2);
        a3 = fmaf(g, w.w, a3);
    }
#pragma unroll
    for (int off = 32; off > 0; off >>= 1) {
        a0 += __shfl_xor(a0, off);
        a1 += __shfl_xor(a1, off);
        a2 += __shfl_xor(a2, off);
        a3 += __shfl_xor(a3, off);
    }
    if (lane == 0) {
        float l0 = a0 + b2[0], l1 = a1 + b2[1], l2 = a2 + b2[2], l3 = a3 + b2[3];
        int e = 0;
        float m = l0;
        if (l1 > m) { m = l1; e = 1; }
        if (l2 > m) { m = l2; e = 2; }
        if (l3 > m) { m = l3; e = 3; }
        float s = __expf(l0 - m) + __expf(l1 - m) + __expf(l2 - m) + __expf(l3 - m);
        idx[n] = e;
        gval[n] = 1.0f / s;
    }
}

__global__ __launch_bounds__(256) void k_count(const int* __restrict__ idx,
                                               int* __restrict__ counts) {
    int n = blockIdx.x * 256 + threadIdx.x;
    int e = idx[n];
#pragma unroll
    for (int ee = 0; ee < 4; ++ee)
        if (e == ee) atomicAdd(counts + ee, 1);
}

__global__ void k_prefix(const int* __restrict__ counts, int* __restrict__ offs,
                         int* __restrict__ cursors) {
    if (threadIdx.x == 0 && blockIdx.x == 0) {
        int o = 0;
        for (int e = 0; e < 4; ++e) {
            offs[e] = o;
            cursors[e] = o;
            o += counts[e];
        }
        offs[4] = o;
    }
}

__global__ __launch_bounds__(256) void k_scatter(const int* __restrict__ idx,
                                                 int* __restrict__ cursors,
                                                 int* __restrict__ perm) {
    int n = blockIdx.x * 256 + threadIdx.x;
    int e = idx[n];
#pragma unroll
    for (int ee = 0; ee < 4; ++ee)
        if (e == ee) {
            int pos = atomicAdd(cursors + ee, 1);
            perm[pos] = n;
        }
}

// bf16 MFMA expert layer. 64 tokens x 64 couts per block, 4 waves (16x64 each).
// FIRST: H[ofs+p] = gelu(Xb[perm] @ W1T^T + b1)
// else : out32    = (H @ W2T^T + b2) * gval + s32, scattered to BCHW; plus
//        260 fused copy blocks restoring the (now dead) mid-lived scratch.
template <bool FIRST>
__global__ __launch_bounds__(256) void k_expert(const short* __restrict__ Abuf,
                                                const short* __restrict__ WT,
                                                const float* __restrict__ EB,
                                                const int* __restrict__ perm,
                                                const int* __restrict__ counts,
                                                const int* __restrict__ offs,
                                                const float* __restrict__ gval,
                                                const float* __restrict__ s32,
                                                short* __restrict__ Hh,
                                                float* __restrict__ out32,
                                                const char* __restrict__ s4b,
                                                char* __restrict__ bb) {
    int bid = blockIdx.x;
    if (!FIRST && bid >= 6144) {
        size_t off = (size_t)MIDB + (size_t)(bid - 6144) * CHUNK;
        copy_chunk_raw(s4b + off, bb + off);
        return;
    }
    __shared__ __align__(16) short As[4096];
    __shared__ __align__(16) short Bs[4096];
    int slot = bid / 12;
    int c0 = (bid % 12) * 64;
    int e = slot >> 7, ts = slot & 127;
    int cnt = counts[e];
    if (ts * 64 >= cnt) return;
    int ofs = offs[e];
    int t = threadIdx.x;
    int lane = t & 63, w = t >> 6;

    int sr = t >> 2;
    int sc = t & 3;
    int pl = ts * 64 + sr;
    int pc = pl < cnt ? pl : cnt - 1;
    int arow = FIRST ? perm[ofs + pc] : (ofs + pc);
    const short* aptr = Abuf + (size_t)arow * CCH;
    const short* bptr = WT + (size_t)e * CCH * CCH + (size_t)(c0 + sr) * CCH;
    int l_lo = sr & 15, g_hi = sr >> 4;
    int dst0 = ((g_hi * 2 + 0) * 64 + l_lo + 16 * sc) * 8;
    int dst1 = ((g_hi * 2 + 1) * 64 + l_lo + 16 * sc) * 8;

    f32x4 acc[4] = {};
    for (int k0 = 0; k0 < CCH; k0 += 64) {
        *(short8v*)(As + dst0) = *(const short8v*)(aptr + k0 + sc * 8);
        *(short8v*)(As + dst1) = *(const short8v*)(aptr + k0 + 32 + sc * 8);
        *(short8v*)(Bs + dst0) = *(const short8v*)(bptr + k0 + sc * 8);
        *(short8v*)(Bs + dst1) = *(const short8v*)(bptr + k0 + 32 + sc * 8);
        __syncthreads();
#pragma unroll
        for (int kk = 0; kk < 2; ++kk) {
            short8v a = *(const short8v*)(As + ((w * 2 + kk) * 64 + lane) * 8);
#pragma unroll
            for (int nt = 0; nt < 4; ++nt) {
                short8v b = *(const short8v*)(Bs + ((nt * 2 + kk) * 64 + lane) * 8);
                acc[nt] = __builtin_amdgcn_mfma_f32_16x16x32_bf16(a, b, acc[nt], 0, 0, 0);
            }
        }
        __syncthreads();
    }

#pragma unroll
    for (int nt = 0; nt < 4; ++nt) {
        int col = c0 + nt * 16 + (lane & 15);
        float bias = EB[e * CCH + col];
#pragma unroll
        for (int r = 0; r < 4; ++r) {
            int p = ts * 64 + w * 16 + (lane >> 4) * 4 + r;
            if (p < cnt) {
                float v = acc[nt][r] + bias;
                if (FIRST) {
                    Hh[(size_t)(ofs + p) * CCH + col] = f2b(gelu_tanh(v));
                } else {
                    int n = perm[ofs + p];
                    float gv = gval[n];
                    int b = n >> 10, hw = n & 1023;
                    size_t addr = ((size_t)(b * CCH + col) << 10) | (size_t)hw;
                    out32[addr] = fmaf(v, gv, s32[addr]);
                }
            }
        }
    }
}

extern "C" void kernel_launch(void* const* d_in, const int* in_sizes, int n_in,
                              void* d_out, int out_size, void* d_ws, size_t ws_size,
                              hipStream_t stream) {
    const float* s4  = (const float*)d_in[0];
    const float* s8  = (const float*)d_in[1];
    const float* s16 = (const float*)d_in[2];
    const float* s32 = (const float*)d_in[3];
    const float* gw1 = (const float*)d_in[4];
    const float* gb1 = (const float*)d_in[5];
    const float* gw2 = (const float*)d_in[6];
    const float* gb2 = (const float*)d_in[7];
    const float* ew1 = (const float*)d_in[8];
    const float* eb1 = (const float*)d_in[9];
    const float* ew2 = (const float*)d_in[10];
    const float* eb2 = (const float*)d_in[11];

    char* bb = (char*)d_out;
    short* Hh      = (short*)bb;
    short* W2T     = (short*)(bb + 12582912);
    int*   idx     = (int*)(bb + 17301504);
    int*   perm    = (int*)(bb + 17334272);
    int*   counts  = (int*)(bb + 17367040);
    int*   offs    = (int*)(bb + 17367104);
    int*   cursors = (int*)(bb + 17367168);
    float* gval    = (float*)(bb + 17367232);
    float* Xg      = (float*)(bb + 18874368);
    short* Xb      = (short*)(bb + 44040192);
    float* G       = (float*)(bb + 56623104);
    short* W1T     = (short*)(bb + 81788928);
    float* out32   = (float*)(bb + 352321536);

    k_transpose<<<dim3(32, 24, 8), dim3(32, 8), 0, stream>>>(s32, Xg, Xb, counts);
    k_cvtw<<<dim3(24, 24, 8), dim3(32, 8), 0, stream>>>(ew1, ew2, W1T, W2T);
    k_gate1<<<1536 + N_EARLY, 256, 0, stream>>>(Xg, gw1, gb1, G,
                                                (const char*)s4, (const char*)s8,
                                                (const char*)s16, bb);
    k_gate2<<<2048, 256, 0, stream>>>(G, gw2, gb2, idx, gval);
    k_count<<<32, 256, 0, stream>>>(idx, counts);
    k_prefix<<<1, 64, 0, stream>>>(counts, offs, cursors);
    k_scatter<<<32, 256, 0, stream>>>(idx, cursors, perm);
    k_expert<true><<<6144, 256, 0, stream>>>(Xb, W1T, eb1, perm, counts, offs,
                                             gval, s32, Hh, out32,
                                             (const char*)s4, bb);
    k_expert<false><<<6144 + N_MID, 256, 0, stream>>>(Hh, W2T, eb2, perm, counts,
                                                      offs, gval, s32, Hh, out32,
                                                      (const char*)s4, bb);
    // restore long-lived scratch region with the real s4 data
    hipMemcpyAsync(bb, s4, (size_t)MIDB, hipMemcpyDeviceToDevice, stream);
}

// Round 4
// 463.651 us; speedup vs baseline: 1.5453x; 1.1378x over previous
//
#include <hip/hip_runtime.h>
#include <cstddef>

#define CCH 768
#define NTOK 8192

typedef __attribute__((ext_vector_type(8))) short short8v;
typedef __attribute__((ext_vector_type(4))) float f32x4;

// ---- copy-chunk plan (256 KiB units) over d_out's s4 region ----
// [0,163)    long-lived scratch: Yt, Hh, W2T, aux     -> tail memcpy
// [163,247)  Xh, W1T, GWh, GWl (dead after exp1)      -> copied in exp2
// [247,391)  Xl, G (dead after gate2)                 -> copied in exp1 (+s16)
// [391,768)  untouched early region                   -> copied in gate1 (+s8)
#define CHUNK 262144u
#define OFF_YT   0u
#define OFF_HH   25165824u
#define OFF_W2T  37748736u
#define OFF_AUX  42467328u
#define TAILBYTES 42729472u
#define OFF_XH   42729472u
#define OFF_W1T  55312384u
#define OFF_GWH  60030976u
#define OFF_GWL  62390272u
#define OFF_XL   64749568u
#define OFF_G    77332480u
#define S8DST    201326592u
#define S16DST   301989888u
#define OUTDST   352321536u

__device__ __forceinline__ void copy_chunk_raw(const char* src, char* dst) {
    const uint4* s = (const uint4*)src;
    uint4* d = (uint4*)dst;
    int t = threadIdx.x;
#pragma unroll 8
    for (int it = 0; it < 64; ++it) d[it * 256 + t] = s[it * 256 + t];
}

__device__ __forceinline__ float gelu_tanh(float x) {
    // JAX default gelu (approximate=True)
    float u = 0.7978845608028654f * (x + 0.044715f * x * x * x);
    float e = __expf(2.0f * u);
    float t = 1.0f - 2.0f / (e + 1.0f);
    return 0.5f * x * (1.0f + t);
}

__device__ __forceinline__ short f2b(float f) {
    unsigned u = __float_as_uint(f);
    unsigned r = (u + 0x7FFFu + ((u >> 16) & 1u)) >> 16;
    return (short)r;
}

// BCHW (8,768,32,32) -> token-major bf16 hi/lo pair; zero counts
__global__ __launch_bounds__(256) void k_transpose(const float* __restrict__ src,
                                                   short* __restrict__ Xh,
                                                   short* __restrict__ Xl,
                                                   int* __restrict__ counts) {
    if (blockIdx.x == 0 && blockIdx.y == 0 && blockIdx.z == 0 &&
        threadIdx.y == 0 && threadIdx.x < 16)
        counts[threadIdx.x] = 0;
    __shared__ float tile[32][33];
    int b = blockIdx.z;
    int c0 = blockIdx.y * 32, hw0 = blockIdx.x * 32;
    int tx = threadIdx.x, ty = threadIdx.y;
    const float* s = src + (size_t)b * CCH * 1024;
#pragma unroll
    for (int i = 0; i < 4; ++i)
        tile[ty + 8 * i][tx] = s[(size_t)(c0 + ty + 8 * i) * 1024 + hw0 + tx];
    __syncthreads();
#pragma unroll
    for (int i = 0; i < 4; ++i) {
        int r = ty + 8 * i;
        int n = b * 1024 + hw0 + r;
        float v = tile[tx][r];
        short h = f2b(v);
        float vh = __uint_as_float(((unsigned)(unsigned short)h) << 16);
        Xh[(size_t)n * CCH + c0 + tx] = h;
        Xl[(size_t)n * CCH + c0 + tx] = f2b(v - vh);
    }
}

// weights -> bf16 transposed [cout][cin]; z=0: gate W1 (hi+lo), z=1..4: ew1, z=5..8: ew2
__global__ __launch_bounds__(256) void k_cvtw(const float* __restrict__ gw1,
                                              const float* __restrict__ ew1,
                                              const float* __restrict__ ew2,
                                              short* __restrict__ GWh,
                                              short* __restrict__ GWl,
                                              short* __restrict__ W1T,
                                              short* __restrict__ W2T) {
    __shared__ float tile[32][33];
    int z = blockIdx.z;
    const float* src;
    short *d1, *d2 = nullptr;
    if (z == 0) { src = gw1; d1 = GWh; d2 = GWl; }
    else if (z <= 4) { src = ew1 + (size_t)(z - 1) * CCH * CCH; d1 = W1T + (size_t)(z - 1) * CCH * CCH; }
    else { src = ew2 + (size_t)(z - 5) * CCH * CCH; d1 = W2T + (size_t)(z - 5) * CCH * CCH; }
    int ci0 = blockIdx.x * 32, co0 = blockIdx.y * 32;
    int tx = threadIdx.x, ty = threadIdx.y;
#pragma unroll
    for (int i = 0; i < 4; ++i)
        tile[ty + 8 * i][tx] = src[(size_t)(ci0 + ty + 8 * i) * CCH + co0 + tx];
    __syncthreads();
#pragma unroll
    for (int i = 0; i < 4; ++i) {
        int co = co0 + ty + 8 * i;
        float v = tile[tx][ty + 8 * i];
        short h = f2b(v);
        d1[(size_t)co * CCH + ci0 + tx] = h;
        if (d2) {
            float vh = __uint_as_float(((unsigned)(unsigned short)h) << 16);
            d2[(size_t)co * CCH + ci0 + tx] = f2b(v - vh);
        }
    }
}

// 128x128-tile MFMA GEMM, 4 waves each owning a 64x64 quadrant (m97 geometry).
// MODE 0: G = gelu((Xh+Xl)@(GWh+GWl)^T + gb1)  split-bf16, ~f32 precision
// MODE 1: Hh[ofs+p] = f2b(gelu(Xh[perm] @ W1T^T + eb1))
// MODE 2: Yt[perm[ofs+p]] = (Hh @ W2T^T + eb2) * gval   (token-major, coalesced)
// Copy blocks appended after ngemm GEMM blocks per the chunk plan above.
template <int MODE>
__global__ __launch_bounds__(256) void k_mfma(const short* __restrict__ Ahp,
                                              const short* __restrict__ Alp,
                                              const short* __restrict__ Bhp,
                                              const short* __restrict__ Blp,
                                              const float* __restrict__ bias,
                                              const int* __restrict__ perm,
                                              const int* __restrict__ counts,
                                              const int* __restrict__ offs,
                                              const float* __restrict__ gval,
                                              float* __restrict__ Gout,
                                              short* __restrict__ Hout,
                                              const char* __restrict__ csrc1,
                                              const char* __restrict__ csrc2,
                                              char* __restrict__ bb,
                                              int ngemm) {
    int bid = blockIdx.x;
    if (bid >= ngemm) {
        int i = bid - ngemm;
        if (MODE == 0) {
            if (i < 377) { size_t c = (size_t)(391 + i) * CHUNK; copy_chunk_raw(csrc1 + c, bb + c); }
            else { size_t o = (size_t)(i - 377) * CHUNK; copy_chunk_raw(csrc2 + o, bb + S8DST + o); }
        } else if (MODE == 1) {
            if (i < 144) { size_t c = (size_t)(247 + i) * CHUNK; copy_chunk_raw(csrc1 + c, bb + c); }
            else { size_t o = (size_t)(i - 144) * CHUNK; copy_chunk_raw(csrc2 + o, bb + S16DST + o); }
        } else {
            size_t c = (size_t)(163 + i) * CHUNK; copy_chunk_raw(csrc1 + c, bb + c);
        }
        return;
    }
    int mt = bid / 6;
    int c0 = (bid % 6) * 128;
    int e = 0, ts = mt, cnt = 1 << 30, ofs = 0, mrow0 = 0;
    if (MODE == 0) {
        mrow0 = mt * 128;
    } else {
        e = mt >> 6;
        ts = mt & 63;
        cnt = counts[e];
        if (ts * 128 >= cnt) return;
        ofs = offs[e];
    }
    __shared__ __align__(16) short lds[(MODE == 0) ? 32768 : 16384];
    short* Ah = lds;
    short* Bh = lds + 8192;
    short* Al = lds + 16384;
    short* Bl = lds + 24576;

    int t = threadIdx.x;
    int lane = t & 63, w = t >> 6;
    int wr = w >> 1, wc = w & 1;

    // staging: thread t stages row r of A and of B, k-half ph (32 shorts each)
    int r = t & 127, ph = t >> 7;
    const short* aptr;
    const short* alptr = nullptr;
    if (MODE == 0) {
        aptr = Ahp + (size_t)(mrow0 + r) * CCH;
        alptr = Alp + (size_t)(mrow0 + r) * CCH;
    } else if (MODE == 1) {
        int pl = ts * 128 + r;
        int pc = pl < cnt ? pl : cnt - 1;
        aptr = Ahp + (size_t)perm[ofs + pc] * CCH;
    } else {
        int pl = ts * 128 + r;
        int pc = pl < cnt ? pl : cnt - 1;
        aptr = Ahp + (size_t)(ofs + pc) * CCH;
    }
    const short* bptr = Bhp + (MODE ? (size_t)e * CCH * CCH : 0) + (size_t)(c0 + r) * CCH;
    const short* blptr = (MODE == 0) ? (Blp + (size_t)(c0 + r) * CCH) : nullptr;
    // fragment-major LDS dest: group (r>>4), kk=ph, lane=(r&15)+16*j
    int dstA = (((r >> 4) * 2 + ph) * 64 + (r & 15)) * 8;

    f32x4 acc[4][4] = {};
    for (int k0 = 0; k0 < CCH; k0 += 64) {
        const short* as = aptr + k0 + ph * 32;
        const short* bs = bptr + k0 + ph * 32;
#pragma unroll
        for (int j = 0; j < 4; ++j) {
            *(short8v*)(Ah + dstA + j * 128) = *(const short8v*)(as + j * 8);
            *(short8v*)(Bh + dstA + j * 128) = *(const short8v*)(bs + j * 8);
        }
        if (MODE == 0) {
            const short* as2 = alptr + k0 + ph * 32;
            const short* bs2 = blptr + k0 + ph * 32;
#pragma unroll
            for (int j = 0; j < 4; ++j) {
                *(short8v*)(Al + dstA + j * 128) = *(const short8v*)(as2 + j * 8);
                *(short8v*)(Bl + dstA + j * 128) = *(const short8v*)(bs2 + j * 8);
            }
        }
        __syncthreads();
#pragma unroll
        for (int kk = 0; kk < 2; ++kk) {
            short8v af[4], bf[4];
#pragma unroll
            for (int m = 0; m < 4; ++m)
                af[m] = *(const short8v*)(Ah + (((wr * 4 + m) * 2 + kk) * 64 + lane) * 8);
#pragma unroll
            for (int n = 0; n < 4; ++n)
                bf[n] = *(const short8v*)(Bh + (((wc * 4 + n) * 2 + kk) * 64 + lane) * 8);
#pragma unroll
            for (int m = 0; m < 4; ++m)
#pragma unroll
                for (int n = 0; n < 4; ++n)
                    acc[m][n] = __builtin_amdgcn_mfma_f32_16x16x32_bf16(af[m], bf[n], acc[m][n], 0, 0, 0);
            if (MODE == 0) {
                short8v blf[4], alf[4];
#pragma unroll
                for (int n = 0; n < 4; ++n)
                    blf[n] = *(const short8v*)(Bl + (((wc * 4 + n) * 2 + kk) * 64 + lane) * 8);
#pragma unroll
                for (int m = 0; m < 4; ++m)
#pragma unroll
                    for (int n = 0; n < 4; ++n)
                        acc[m][n] = __builtin_amdgcn_mfma_f32_16x16x32_bf16(af[m], blf[n], acc[m][n], 0, 0, 0);
#pragma unroll
                for (int m = 0; m < 4; ++m)
                    alf[m] = *(const short8v*)(Al + (((wr * 4 + m) * 2 + kk) * 64 + lane) * 8);
#pragma unroll
                for (int m = 0; m < 4; ++m)
#pragma unroll
                    for (int n = 0; n < 4; ++n)
                        acc[m][n] = __builtin_amdgcn_mfma_f32_16x16x32_bf16(alf[m], bf[n], acc[m][n], 0, 0, 0);
            }
        }
        __syncthreads();
    }

    int cl = lane & 15, rh = (lane >> 4) * 4;
#pragma unroll
    for (int n = 0; n < 4; ++n) {
        int col = c0 + wc * 64 + n * 16 + cl;
        float bv = (MODE == 0) ? bias[col] : bias[e * CCH + col];
#pragma unroll
        for (int m = 0; m < 4; ++m) {
#pragma unroll
            for (int ri = 0; ri < 4; ++ri) {
                int rr = wr * 64 + m * 16 + rh + ri;
                float v = acc[m][n][ri] + bv;
                if (MODE == 0) {
                    Gout[(size_t)(mrow0 + rr) * CCH + col] = gelu_tanh(v);
                } else {
                    int p = ts * 128 + rr;
                    if (p < cnt) {
                        if (MODE == 1) {
                            Hout[(size_t)(ofs + p) * CCH + col] = f2b(gelu_tanh(v));
                        } else {
                            int nn = perm[ofs + p];
                            Gout[(size_t)nn * CCH + col] = v * gval[nn];
                        }
                    }
                }
            }
        }
    }
}

// logits = G @ W2 + b2 -> top1 idx, gate value, per-expert counts
__global__ __launch_bounds__(256) void k_gate2(const float* __restrict__ G,
                                               const float* __restrict__ W2,
                                               const float* __restrict__ b2,
                                               int* __restrict__ idx,
                                               float* __restrict__ gval,
                                               int* __restrict__ counts) {
    int t = threadIdx.x;
    int lane = t & 63, wid = t >> 6;
    int n = blockIdx.x * 4 + wid;
    const float* gr = G + (size_t)n * CCH;
    float a0 = 0.f, a1 = 0.f, a2 = 0.f, a3 = 0.f;
#pragma unroll
    for (int i = 0; i < 12; ++i) {
        int c = lane + 64 * i;
        float g = gr[c];
        float4 w = *(const float4*)(W2 + c * 4);
        a0 = fmaf(g, w.x, a0);
        a1 = fmaf(g, w.y, a1);
        a2 = fmaf(g, w.z, a2);
        a3 = fmaf(g, w.w, a3);
    }
#pragma unroll
    for (int off = 32; off > 0; off >>= 1) {
        a0 += __shfl_xor(a0, off);
        a1 += __shfl_xor(a1, off);
        a2 += __shfl_xor(a2, off);
        a3 += __shfl_xor(a3, off);
    }
    if (lane == 0) {
        float l0 = a0 + b2[0], l1 = a1 + b2[1], l2 = a2 + b2[2], l3 = a3 + b2[3];
        int e = 0;
        float m = l0;
        if (l1 > m) { m = l1; e = 1; }
        if (l2 > m) { m = l2; e = 2; }
        if (l3 > m) { m = l3; e = 3; }
        float s = __expf(l0 - m) + __expf(l1 - m) + __expf(l2 - m) + __expf(l3 - m);
        idx[n] = e;
        gval[n] = 1.0f / s;
        atomicAdd(counts + e, 1);
    }
}

__global__ void k_prefix(const int* __restrict__ counts, int* __restrict__ offs,
                         int* __restrict__ cursors) {
    if (threadIdx.x == 0 && blockIdx.x == 0) {
        int o = 0;
        for (int e = 0; e < 4; ++e) {
            offs[e] = o;
            cursors[e] = o;
            o += counts[e];
        }
        offs[4] = o;
    }
}

__global__ __launch_bounds__(256) void k_scatter(const int* __restrict__ idx,
                                                 int* __restrict__ cursors,
                                                 int* __restrict__ perm) {
    int n = blockIdx.x * 256 + threadIdx.x;
    int e = idx[n];
#pragma unroll
    for (int ee = 0; ee < 4; ++ee)
        if (e == ee) {
            int pos = atomicAdd(cursors + ee, 1);
            perm[pos] = n;
        }
}

// out32 = Yt (token-major) + s32, both sides fully coalesced
__global__ __launch_bounds__(256) void k_untr(const float* __restrict__ Yt,
                                              const float* __restrict__ s32,
                                              float* __restrict__ out32) {
    __shared__ float tile[32][33];
    int b = blockIdx.z;
    int c0 = blockIdx.y * 32, hw0 = blockIdx.x * 32;
    int tx = threadIdx.x, ty = threadIdx.y;
#pragma unroll
    for (int i = 0; i < 4; ++i) {
        int hwl = ty + 8 * i;
        tile[hwl][tx] = Yt[(size_t)(b * 1024 + hw0 + hwl) * CCH + c0 + tx];
    }
    __syncthreads();
    const float* sp = s32 + (size_t)b * CCH * 1024;
    float* op = out32 + (size_t)b * CCH * 1024;
#pragma unroll
    for (int i = 0; i < 4; ++i) {
        size_t a = (size_t)(c0 + ty + 8 * i) * 1024 + hw0 + tx;
        op[a] = tile[tx][ty + 8 * i] + sp[a];
    }
}

extern "C" void kernel_launch(void* const* d_in, const int* in_sizes, int n_in,
                              void* d_out, int out_size, void* d_ws, size_t ws_size,
                              hipStream_t stream) {
    const float* s4  = (const float*)d_in[0];
    const float* s8  = (const float*)d_in[1];
    const float* s16 = (const float*)d_in[2];
    const float* s32 = (const float*)d_in[3];
    const float* gw1 = (const float*)d_in[4];
    const float* gb1 = (const float*)d_in[5];
    const float* gw2 = (const float*)d_in[6];
    const float* gb2 = (const float*)d_in[7];
    const float* ew1 = (const float*)d_in[8];
    const float* eb1 = (const float*)d_in[9];
    const float* ew2 = (const float*)d_in[10];
    const float* eb2 = (const float*)d_in[11];

    char* bb = (char*)d_out;
    float* Yt   = (float*)(bb + OFF_YT);
    short* Hh   = (short*)(bb + OFF_HH);
    short* W2T  = (short*)(bb + OFF_W2T);
    int* iaux   = (int*)(bb + OFF_AUX);
    int* idx     = iaux;
    int* perm    = iaux + 8192;
    int* counts  = iaux + 16384;
    int* offs    = iaux + 16400;
    int* cursors = iaux + 16408;
    float* gval  = (float*)(iaux + 16416);
    short* Xh   = (short*)(bb + OFF_XH);
    short* W1T  = (short*)(bb + OFF_W1T);
    short* GWh  = (short*)(bb + OFF_GWH);
    short* GWl  = (short*)(bb + OFF_GWL);
    short* Xl   = (short*)(bb + OFF_XL);
    float* G    = (float*)(bb + OFF_G);
    float* out32 = (float*)(bb + OUTDST);

    k_transpose<<<dim3(32, 24, 8), dim3(32, 8), 0, stream>>>(s32, Xh, Xl, counts);
    k_cvtw<<<dim3(24, 24, 9), dim3(32, 8), 0, stream>>>(gw1, ew1, ew2, GWh, GWl, W1T, W2T);
    // gate layer 1 (split-bf16) + early-region/s8 copies
    k_mfma<0><<<384 + 761, 256, 0, stream>>>(Xh, Xl, GWh, GWl, gb1, perm, counts,
                                             offs, gval, G, Hh,
                                             (const char*)s4, (const char*)s8, bb, 384);
    k_gate2<<<2048, 256, 0, stream>>>(G, gw2, gb2, idx, gval, counts);
    k_prefix<<<1, 64, 0, stream>>>(counts, offs, cursors);
    k_scatter<<<32, 256, 0, stream>>>(idx, cursors, perm);
    // expert layer 1 + Xl/G-region/s16 copies
    k_mfma<1><<<1536 + 336, 256, 0, stream>>>(Xh, Xl, W1T, GWl, eb1, perm, counts,
                                              offs, gval, G, Hh,
                                              (const char*)s4, (const char*)s16, bb, 1536);
    // expert layer 2 + Xh/W1T/GW-region copies
    k_mfma<2><<<1536 + 84, 256, 0, stream>>>(Hh, Xl, W2T, GWl, eb2, perm, counts,
                                             offs, gval, Yt, Hh,
                                             (const char*)s4, (const char*)s16, bb, 1536);
    k_untr<<<dim3(32, 24, 8), dim3(32, 8), 0, stream>>>(Yt, s32, out32);
    // restore long-lived scratch region
    hipMemcpyAsync(bb, s4, (size_t)TAILBYTES, hipMemcpyDeviceToDevice, stream);
}

// Round 5
// 431.598 us; speedup vs baseline: 1.6601x; 1.0743x over previous
//
#include <hip/hip_runtime.h>
#include <cstddef>

#define CCH 768
#define NTOK 8192

typedef __attribute__((ext_vector_type(8))) short short8v;
typedef __attribute__((ext_vector_type(4))) float f32x4;

// ---- copy-chunk plan (256 KiB units) over d_out's s4 region ----
// [0,163)    long-lived: Yt, Hh, W2T, aux            -> tail memcpy
// [163,247)  Xh, W1T, GWh, GWl (dead after exp1)     -> copied in exp2
// [247,391)  Xl, G (dead after gate2)                -> copied in exp1
// [391,768)  untouched early region                  -> copied in gate1 (+s8)
// s16 output region                                  -> copied in exp2
#define CHUNK 262144u
#define OFF_YT   0u
#define OFF_HH   25165824u
#define OFF_W2T  37748736u
#define OFF_AUX  42467328u
#define TAILBYTES 42729472u
#define OFF_XH   42729472u
#define OFF_W1T  55312384u
#define OFF_GWH  60030976u
#define OFF_GWL  62390272u
#define OFF_XL   64749568u
#define OFF_G    77332480u
#define S8DST    201326592u
#define S16DST   301989888u
#define OUTDST   352321536u

__device__ __forceinline__ void gl16(const void* g, void* l) {
    __builtin_amdgcn_global_load_lds(
        (const __attribute__((address_space(1))) void*)g,
        (__attribute__((address_space(3))) void*)l, 16, 0, 0);
}

__device__ __forceinline__ void copy_chunk_raw(const char* src, char* dst) {
    const uint4* s = (const uint4*)src;
    uint4* d = (uint4*)dst;
    int t = threadIdx.x;
#pragma unroll 8
    for (int it = 0; it < 64; ++it) d[it * 256 + t] = s[it * 256 + t];
}

__device__ __forceinline__ float gelu_tanh(float x) {
    // JAX default gelu (approximate=True)
    float u = 0.7978845608028654f * (x + 0.044715f * x * x * x);
    float e = __expf(2.0f * u);
    float t = 1.0f - 2.0f / (e + 1.0f);
    return 0.5f * x * (1.0f + t);
}

__device__ __forceinline__ short f2b(float f) {
    unsigned u = __float_as_uint(f);
    unsigned r = (u + 0x7FFFu + ((u >> 16) & 1u)) >> 16;
    return (short)r;
}

// z<8: BCHW->token-major bf16 hi/lo transpose (batch z). z>=8: weight convert
// (z-8): 0 -> gate W1 hi+lo, 1..4 -> ew1, 5..8 -> ew2. Also zeroes counts+cursors.
__global__ __launch_bounds__(256) void k_prep(const float* __restrict__ s32,
                                              const float* __restrict__ gw1,
                                              const float* __restrict__ ew1,
                                              const float* __restrict__ ew2,
                                              short* __restrict__ Xh,
                                              short* __restrict__ Xl,
                                              short* __restrict__ GWh,
                                              short* __restrict__ GWl,
                                              short* __restrict__ W1T,
                                              short* __restrict__ W2T,
                                              int* __restrict__ az) {
    int z = blockIdx.z;
    int tx = threadIdx.x, ty = threadIdx.y;
    if (z == 0 && blockIdx.x == 0 && blockIdx.y == 0 && ty == 0 && tx < 8)
        az[tx] = 0;
    __shared__ float tile[32][33];
    if (z < 8) {
        int c0 = blockIdx.y * 32, hw0 = blockIdx.x * 32;
        const float* s = s32 + (size_t)z * CCH * 1024;
#pragma unroll
        for (int i = 0; i < 4; ++i)
            tile[ty + 8 * i][tx] = s[(size_t)(c0 + ty + 8 * i) * 1024 + hw0 + tx];
        __syncthreads();
#pragma unroll
        for (int i = 0; i < 4; ++i) {
            int r = ty + 8 * i;
            int n = z * 1024 + hw0 + r;
            float v = tile[tx][r];
            short h = f2b(v);
            float vh = __uint_as_float(((unsigned)(unsigned short)h) << 16);
            Xh[(size_t)n * CCH + c0 + tx] = h;
            Xl[(size_t)n * CCH + c0 + tx] = f2b(v - vh);
        }
    } else {
        if (blockIdx.x >= 24) return;
        int w = z - 8;
        const float* src;
        short *d1, *d2 = nullptr;
        if (w == 0) { src = gw1; d1 = GWh; d2 = GWl; }
        else if (w <= 4) { src = ew1 + (size_t)(w - 1) * CCH * CCH; d1 = W1T + (size_t)(w - 1) * CCH * CCH; }
        else { src = ew2 + (size_t)(w - 5) * CCH * CCH; d1 = W2T + (size_t)(w - 5) * CCH * CCH; }
        int ci0 = blockIdx.x * 32, co0 = blockIdx.y * 32;
#pragma unroll
        for (int i = 0; i < 4; ++i)
            tile[ty + 8 * i][tx] = src[(size_t)(ci0 + ty + 8 * i) * CCH + co0 + tx];
        __syncthreads();
#pragma unroll
        for (int i = 0; i < 4; ++i) {
            int co = co0 + ty + 8 * i;
            float v = tile[tx][ty + 8 * i];
            short h = f2b(v);
            d1[(size_t)co * CCH + ci0 + tx] = h;
            if (d2) {
                float vh = __uint_as_float(((unsigned)(unsigned short)h) << 16);
                d2[(size_t)co * CCH + ci0 + tx] = f2b(v - vh);
            }
        }
    }
}

// 128x128-tile MFMA GEMM, 4 waves each owning a 64x64 quadrant; staging via
// global_load_lds(16B) into fragment-major LDS (per-lane pre-swizzled source).
// MODE 0: G = gelu((Xh+Xl)@(GWh+GWl)^T + gb1), BK=32, 4 LDS bufs (32 KB)
// MODE 1: Hh[ofs+p] = f2b(gelu(Xh[perm] @ W1T^T + eb1)), BK=64 (32 KB)
// MODE 2: Yt[perm[ofs+p]] = (Hh @ W2T^T + eb2) * gval,   BK=64 (32 KB)
template <int MODE>
__global__ __launch_bounds__(256) void k_mfma(const short* __restrict__ Ahp,
                                              const short* __restrict__ Alp,
                                              const short* __restrict__ Bhp,
                                              const short* __restrict__ Blp,
                                              const float* __restrict__ bias,
                                              const int* __restrict__ perm,
                                              const int* __restrict__ counts,
                                              const float* __restrict__ gval,
                                              float* __restrict__ Gout,
                                              short* __restrict__ Hout,
                                              const char* __restrict__ csrc1,
                                              const char* __restrict__ csrc2,
                                              char* __restrict__ bb,
                                              int ngemm) {
    int bid = blockIdx.x;
    if (bid >= ngemm) {
        int i = bid - ngemm;
        if (MODE == 0) {
            if (i < 377) { size_t c = (size_t)(391 + i) * CHUNK; copy_chunk_raw(csrc1 + c, bb + c); }
            else { size_t o = (size_t)(i - 377) * CHUNK; copy_chunk_raw(csrc2 + o, bb + S8DST + o); }
        } else if (MODE == 1) {
            size_t c = (size_t)(247 + i) * CHUNK; copy_chunk_raw(csrc1 + c, bb + c);
        } else {
            if (i < 84) { size_t c = (size_t)(163 + i) * CHUNK; copy_chunk_raw(csrc1 + c, bb + c); }
            else { size_t o = (size_t)(i - 84) * CHUNK; copy_chunk_raw(csrc2 + o, bb + S16DST + o); }
        }
        return;
    }
    int mt = bid / 6;
    int c0 = (bid % 6) * 128;
    int e = 0, ts = mt, cnt = 1 << 30, ofs = 0, mrow0 = 0;
    if (MODE == 0) {
        mrow0 = mt * 128;
    } else {
        e = mt >> 6;
        ts = mt & 63;
        int n0 = counts[0], n1 = counts[1], n2 = counts[2], n3 = counts[3];
        cnt = (e == 0) ? n0 : (e == 1) ? n1 : (e == 2) ? n2 : n3;
        if (ts * 128 >= cnt) return;
        ofs = (e > 0 ? n0 : 0) + (e > 1 ? n1 : 0) + (e > 2 ? n2 : 0);
    }
    __shared__ __align__(16) short lds[16384];

    int t = threadIdx.x;
    int lane = t & 63, w = t >> 6;
    int wr = w >> 1, wc = w & 1;
    int lrow = lane & 15, lk8 = lane >> 4;

    const short* aS[4];
    const short* bS[4];
    const short* alS[2];
    const short* blS[2];
    short* aD[4];
    short* bD[4];
    short* alD[2];
    short* blD[2];

    if (MODE == 0) {
#pragma unroll
        for (int i = 0; i < 2; ++i) {
            int c = 2 * w + i;
            int row = c * 16 + lrow;
            int koff = lk8 * 8;
            aS[i]  = Ahp + (size_t)(mrow0 + row) * CCH + koff;
            alS[i] = Alp + (size_t)(mrow0 + row) * CCH + koff;
            bS[i]  = Bhp + (size_t)(c0 + row) * CCH + koff;
            blS[i] = Blp + (size_t)(c0 + row) * CCH + koff;
            aD[i]  = lds + c * 512;
            bD[i]  = lds + 4096 + c * 512;
            alD[i] = lds + 8192 + c * 512;
            blD[i] = lds + 12288 + c * 512;
        }
    } else {
        size_t eoff = (size_t)e * CCH * CCH;
#pragma unroll
        for (int i = 0; i < 4; ++i) {
            int c = 4 * w + i;
            int g = c >> 1, ph = c & 1;
            int row = g * 16 + lrow;
            int koff = ph * 32 + lk8 * 8;
            int pl = ts * 128 + row;
            int pc = pl < cnt ? pl : cnt - 1;
            int tokrow = (MODE == 1) ? perm[ofs + pc] : (ofs + pc);
            aS[i] = Ahp + (size_t)tokrow * CCH + koff;
            bS[i] = Bhp + eoff + (size_t)(c0 + row) * CCH + koff;
            aD[i] = lds + c * 512;
            bD[i] = lds + 8192 + c * 512;
        }
    }

    f32x4 acc[4][4] = {};
    if (MODE == 0) {
        for (int k0 = 0; k0 < CCH; k0 += 32) {
#pragma unroll
            for (int i = 0; i < 2; ++i) {
                gl16(aS[i] + k0, aD[i]);
                gl16(bS[i] + k0, bD[i]);
                gl16(alS[i] + k0, alD[i]);
                gl16(blS[i] + k0, blD[i]);
            }
            __syncthreads();
            short8v af[4], bf[4], xf[4];
#pragma unroll
            for (int m = 0; m < 4; ++m)
                af[m] = *(const short8v*)(lds + ((wr * 4 + m) * 64 + lane) * 8);
#pragma unroll
            for (int n = 0; n < 4; ++n)
                bf[n] = *(const short8v*)(lds + 4096 + ((wc * 4 + n) * 64 + lane) * 8);
#pragma unroll
            for (int m = 0; m < 4; ++m)
#pragma unroll
                for (int n = 0; n < 4; ++n)
                    acc[m][n] = __builtin_amdgcn_mfma_f32_16x16x32_bf16(af[m], bf[n], acc[m][n], 0, 0, 0);
#pragma unroll
            for (int n = 0; n < 4; ++n)
                xf[n] = *(const short8v*)(lds + 12288 + ((wc * 4 + n) * 64 + lane) * 8);
#pragma unroll
            for (int m = 0; m < 4; ++m)
#pragma unroll
                for (int n = 0; n < 4; ++n)
                    acc[m][n] = __builtin_amdgcn_mfma_f32_16x16x32_bf16(af[m], xf[n], acc[m][n], 0, 0, 0);
#pragma unroll
            for (int m = 0; m < 4; ++m)
                xf[m] = *(const short8v*)(lds + 8192 + ((wr * 4 + m) * 64 + lane) * 8);
#pragma unroll
            for (int m = 0; m < 4; ++m)
#pragma unroll
                for (int n = 0; n < 4; ++n)
                    acc[m][n] = __builtin_amdgcn_mfma_f32_16x16x32_bf16(xf[m], bf[n], acc[m][n], 0, 0, 0);
            __syncthreads();
        }
    } else {
        for (int k0 = 0; k0 < CCH; k0 += 64) {
#pragma unroll
            for (int i = 0; i < 4; ++i) {
                gl16(aS[i] + k0, aD[i]);
                gl16(bS[i] + k0, bD[i]);
            }
            __syncthreads();
#pragma unroll
            for (int kk = 0; kk < 2; ++kk) {
                short8v af[4], bf[4];
#pragma unroll
                for (int m = 0; m < 4; ++m)
                    af[m] = *(const short8v*)(lds + (((wr * 4 + m) * 2 + kk) * 64 + lane) * 8);
#pragma unroll
                for (int n = 0; n < 4; ++n)
                    bf[n] = *(const short8v*)(lds + 8192 + (((wc * 4 + n) * 2 + kk) * 64 + lane) * 8);
#pragma unroll
                for (int m = 0; m < 4; ++m)
#pragma unroll
                    for (int n = 0; n < 4; ++n)
                        acc[m][n] = __builtin_amdgcn_mfma_f32_16x16x32_bf16(af[m], bf[n], acc[m][n], 0, 0, 0);
            }
            __syncthreads();
        }
    }

    int cl = lane & 15, rh = (lane >> 4) * 4;
#pragma unroll
    for (int n = 0; n < 4; ++n) {
        int col = c0 + wc * 64 + n * 16 + cl;
        float bv = (MODE == 0) ? bias[col] : bias[e * CCH + col];
#pragma unroll
        for (int m = 0; m < 4; ++m) {
#pragma unroll
            for (int ri = 0; ri < 4; ++ri) {
                int rr = wr * 64 + m * 16 + rh + ri;
                float v = acc[m][n][ri] + bv;
                if (MODE == 0) {
                    Gout[(size_t)(mrow0 + rr) * CCH + col] = gelu_tanh(v);
                } else {
                    int p = ts * 128 + rr;
                    if (p < cnt) {
                        if (MODE == 1) {
                            Hout[(size_t)(ofs + p) * CCH + col] = f2b(gelu_tanh(v));
                        } else {
                            int nn = perm[ofs + p];
                            Gout[(size_t)nn * CCH + col] = v * gval[nn];
                        }
                    }
                }
            }
        }
    }
}

// logits = G @ W2 + b2 -> top1 idx, gate value, per-expert counts
__global__ __launch_bounds__(256) void k_gate2(const float* __restrict__ G,
                                               const float* __restrict__ W2,
                                               const float* __restrict__ b2,
                                               int* __restrict__ idx,
                                               float* __restrict__ gval,
                                               int* __restrict__ counts) {
    int t = threadIdx.x;
    int lane = t & 63, wid = t >> 6;
    int n = blockIdx.x * 4 + wid;
    const float* gr = G + (size_t)n * CCH;
    float a0 = 0.f, a1 = 0.f, a2 = 0.f, a3 = 0.f;
#pragma unroll
    for (int i = 0; i < 12; ++i) {
        int c = lane + 64 * i;
        float g = gr[c];
        float4 w = *(const float4*)(W2 + c * 4);
        a0 = fmaf(g, w.x, a0);
        a1 = fmaf(g, w.y, a1);
        a2 = fmaf(g, w.z, a2);
        a3 = fmaf(g, w.w, a3);
    }
#pragma unroll
    for (int off = 32; off > 0; off >>= 1) {
        a0 += __shfl_xor(a0, off);
        a1 += __shfl_xor(a1, off);
        a2 += __shfl_xor(a2, off);
        a3 += __shfl_xor(a3, off);
    }
    if (lane == 0) {
        float l0 = a0 + b2[0], l1 = a1 + b2[1], l2 = a2 + b2[2], l3 = a3 + b2[3];
        int e = 0;
        float m = l0;
        if (l1 > m) { m = l1; e = 1; }
        if (l2 > m) { m = l2; e = 2; }
        if (l3 > m) { m = l3; e = 3; }
        float s = __expf(l0 - m) + __expf(l1 - m) + __expf(l2 - m) + __expf(l3 - m);
        idx[n] = e;
        gval[n] = 1.0f / s;
        atomicAdd(counts + e, 1);
    }
}

// scatter with in-register prefix over the 4 finalized counts
__global__ __launch_bounds__(256) void k_scatter(const int* __restrict__ idx,
                                                 const int* __restrict__ counts,
                                                 int* __restrict__ cursors,
                                                 int* __restrict__ perm) {
    int n = blockIdx.x * 256 + threadIdx.x;
    int e = idx[n];
    int run = 0;
#pragma unroll
    for (int ee = 0; ee < 4; ++ee) {
        int c = counts[ee];
        if (e == ee) {
            int pos = run + atomicAdd(cursors + ee, 1);
            perm[pos] = n;
        }
        run += c;
    }
}

// out32 = Yt (token-major) + s32, both sides fully coalesced
__global__ __launch_bounds__(256) void k_untr(const float* __restrict__ Yt,
                                              const float* __restrict__ s32,
                                              float* __restrict__ out32) {
    __shared__ float tile[32][33];
    int b = blockIdx.z;
    int c0 = blockIdx.y * 32, hw0 = blockIdx.x * 32;
    int tx = threadIdx.x, ty = threadIdx.y;
#pragma unroll
    for (int i = 0; i < 4; ++i) {
        int hwl = ty + 8 * i;
        tile[hwl][tx] = Yt[(size_t)(b * 1024 + hw0 + hwl) * CCH + c0 + tx];
    }
    __syncthreads();
    const float* sp = s32 + (size_t)b * CCH * 1024;
    float* op = out32 + (size_t)b * CCH * 1024;
#pragma unroll
    for (int i = 0; i < 4; ++i) {
        size_t a = (size_t)(c0 + ty + 8 * i) * 1024 + hw0 + tx;
        op[a] = tile[tx][ty + 8 * i] + sp[a];
    }
}

extern "C" void kernel_launch(void* const* d_in, const int* in_sizes, int n_in,
                              void* d_out, int out_size, void* d_ws, size_t ws_size,
                              hipStream_t stream) {
    const float* s4  = (const float*)d_in[0];
    const float* s8  = (const float*)d_in[1];
    const float* s16 = (const float*)d_in[2];
    const float* s32 = (const float*)d_in[3];
    const float* gw1 = (const float*)d_in[4];
    const float* gb1 = (const float*)d_in[5];
    const float* gw2 = (const float*)d_in[6];
    const float* gb2 = (const float*)d_in[7];
    const float* ew1 = (const float*)d_in[8];
    const float* eb1 = (const float*)d_in[9];
    const float* ew2 = (const float*)d_in[10];
    const float* eb2 = (const float*)d_in[11];

    char* bb = (char*)d_out;
    float* Yt   = (float*)(bb + OFF_YT);
    short* Hh   = (short*)(bb + OFF_HH);
    short* W2T  = (short*)(bb + OFF_W2T);
    int* iaux   = (int*)(bb + OFF_AUX);
    int* idx     = iaux;
    int* perm    = iaux + 8192;
    int* counts  = iaux + 16384;   // 4 counts + 4 cursors (contiguous, zeroed in prep)
    int* cursors = iaux + 16388;
    float* gval  = (float*)(iaux + 16392);
    short* Xh   = (short*)(bb + OFF_XH);
    short* W1T  = (short*)(bb + OFF_W1T);
    short* GWh  = (short*)(bb + OFF_GWH);
    short* GWl  = (short*)(bb + OFF_GWL);
    short* Xl   = (short*)(bb + OFF_XL);
    float* G    = (float*)(bb + OFF_G);
    float* out32 = (float*)(bb + OUTDST);

    k_prep<<<dim3(32, 24, 17), dim3(32, 8), 0, stream>>>(s32, gw1, ew1, ew2, Xh, Xl,
                                                         GWh, GWl, W1T, W2T, counts);
    // gate layer 1 (split-bf16, 3 MFMA passes) + early-s4/s8 copies
    k_mfma<0><<<384 + 761, 256, 0, stream>>>(Xh, Xl, GWh, GWl, gb1, perm, counts,
                                             gval, G, Hh,
                                             (const char*)s4, (const char*)s8, bb, 384);
    k_gate2<<<2048, 256, 0, stream>>>(G, gw2, gb2, idx, gval, counts);
    k_scatter<<<32, 256, 0, stream>>>(idx, counts, cursors, perm);
    // expert layer 1 + Xl/G-region copies
    k_mfma<1><<<1536 + 144, 256, 0, stream>>>(Xh, Xl, W1T, GWl, eb1, perm, counts,
                                              gval, G, Hh,
                                              (const char*)s4, (const char*)s16, bb, 1536);
    // expert layer 2 + Xh/W1T/GW-region + s16 copies
    k_mfma<2><<<1536 + 276, 256, 0, stream>>>(Hh, Xl, W2T, GWl, eb2, perm, counts,
                                              gval, Yt, Hh,
                                              (const char*)s4, (const char*)s16, bb, 1536);
    k_untr<<<dim3(32, 24, 8), dim3(32, 8), 0, stream>>>(Yt, s32, out32);
    // restore long-lived scratch region with the real s4 data
    hipMemcpyAsync(bb, s4, (size_t)TAILBYTES, hipMemcpyDeviceToDevice, stream);
}

// Round 6
// 371.532 us; speedup vs baseline: 1.9284x; 1.1617x over previous
//
#include <hip/hip_runtime.h>
#include <cstddef>

#define CCH 768
#define CHUNK 262144u

// ---- d_out scratch layout (byte offsets), chunk = 256 KiB ----
// tail [0,170): Yt, Hh, W2T, aux        -> final memcpy
// mid1 [170,227): Xl, GWh, GWl          -> copied in exp1
// mid2 [227,293): Xh, W1T               -> copied in exp2
// early [293,768) + s8                  -> copied in gate1
// s16                                   -> copied half in exp1, half in exp2
#define OFF_YT    0u
#define OFF_HH    25165824u
#define OFF_W2T   37748736u
#define OFF_IDX   42467328u
#define OFF_PERM  42500096u
#define OFF_CNT   42532864u
#define OFF_CUR   42532880u
#define OFF_GVAL  42532896u
#define OFF_PART  42565664u
#define TAILBYTES 44564480u
#define OFF_XL    44564480u
#define OFF_GWH   57147392u
#define OFF_GWL   58327040u
#define OFF_XH    59506688u
#define OFF_W1T   72089600u
#define S8DST     201326592u
#define S16DST    301989888u
#define OUTDST    352321536u

typedef __attribute__((ext_vector_type(8))) short short8v;
typedef __attribute__((ext_vector_type(4))) float f32x4;

__device__ __forceinline__ void gl16(const void* g, void* l) {
    __builtin_amdgcn_global_load_lds(
        (const __attribute__((address_space(1))) void*)g,
        (__attribute__((address_space(3))) void*)l, 16, 0, 0);
}

__device__ __forceinline__ void copy_chunk_raw(const char* src, char* dst) {
    const uint4* s = (const uint4*)src;
    uint4* d = (uint4*)dst;
    int t = threadIdx.x;
#pragma unroll 8
    for (int it = 0; it < 64; ++it) d[it * 256 + t] = s[it * 256 + t];
}

__device__ __forceinline__ float gelu_tanh(float x) {
    // JAX default gelu (approximate=True)
    float u = 0.7978845608028654f * (x + 0.044715f * x * x * x);
    float e = __expf(2.0f * u);
    float t = 1.0f - 2.0f / (e + 1.0f);
    return 0.5f * x * (1.0f + t);
}

__device__ __forceinline__ short f2b(float f) {
    unsigned u = __float_as_uint(f);
    unsigned r = (u + 0x7FFFu + ((u >> 16) & 1u)) >> 16;
    return (short)r;
}

// z<8: BCHW->token-major bf16 hi/lo transpose of s32. z==8: gate W1 hi/lo
// transposed convert. Also zeroes counts/cursors.
__global__ __launch_bounds__(256) void k_prep(const float* __restrict__ s32,
                                              const float* __restrict__ gw1,
                                              short* __restrict__ Xh,
                                              short* __restrict__ Xl,
                                              short* __restrict__ GWh,
                                              short* __restrict__ GWl,
                                              int* __restrict__ az) {
    int z = blockIdx.z;
    int tx = threadIdx.x, ty = threadIdx.y;
    if (z == 0 && blockIdx.x == 0 && blockIdx.y == 0 && ty == 0 && tx < 8)
        az[tx] = 0;
    __shared__ float tile[32][33];
    if (z < 8) {
        int c0 = blockIdx.y * 32, hw0 = blockIdx.x * 32;
        const float* s = s32 + (size_t)z * CCH * 1024;
#pragma unroll
        for (int i = 0; i < 4; ++i)
            tile[ty + 8 * i][tx] = s[(size_t)(c0 + ty + 8 * i) * 1024 + hw0 + tx];
        __syncthreads();
#pragma unroll
        for (int i = 0; i < 4; ++i) {
            int r = ty + 8 * i;
            int n = z * 1024 + hw0 + r;
            float v = tile[tx][r];
            short h = f2b(v);
            float vh = __uint_as_float(((unsigned)(unsigned short)h) << 16);
            Xh[(size_t)n * CCH + c0 + tx] = h;
            Xl[(size_t)n * CCH + c0 + tx] = f2b(v - vh);
        }
    } else {
        if (blockIdx.x >= 24) return;
        int ci0 = blockIdx.x * 32, co0 = blockIdx.y * 32;
#pragma unroll
        for (int i = 0; i < 4; ++i)
            tile[ty + 8 * i][tx] = gw1[(size_t)(ci0 + ty + 8 * i) * CCH + co0 + tx];
        __syncthreads();
#pragma unroll
        for (int i = 0; i < 4; ++i) {
            int co = co0 + ty + 8 * i;
            float v = tile[tx][ty + 8 * i];
            short h = f2b(v);
            GWh[(size_t)co * CCH + ci0 + tx] = h;
            float vh = __uint_as_float(((unsigned)(unsigned short)h) << 16);
            GWl[(size_t)co * CCH + ci0 + tx] = f2b(v - vh);
        }
    }
}

// 128x128-tile MFMA GEMM, 4 waves (64x64 quadrants), 2-phase double-buffered
// global_load_lds pipeline (issue next tile, compute current, one barrier).
// MODE 0: partial logits = (gelu(split-bf16 X@GW^T + gb1)) @ W2-slice, written
//         per (c0-block, wc) to partial[12][8192][4]. No G materialized.
//         Extra blocks: early-s4/s8 copies + ew1/ew2 bf16-transpose converts.
// MODE 1: Hh[ofs+p] = f2b(gelu(Xh[perm] @ W1T^T + eb1)); + mid1/s16 copies
// MODE 2: Yt[perm[ofs+p]] = (Hh @ W2T^T + eb2)*gval;     + mid2/s16 copies
template <int MODE>
__global__ __launch_bounds__(256) void k_mfma(const short* __restrict__ Ahp,
                                              const short* __restrict__ Alp,
                                              const short* __restrict__ Bhp,
                                              const short* __restrict__ Blp,
                                              const float* __restrict__ bias,
                                              const float* __restrict__ gw2,
                                              const int* __restrict__ perm,
                                              const int* __restrict__ counts,
                                              const float* __restrict__ gval,
                                              float* __restrict__ Yt,
                                              short* __restrict__ Hout,
                                              float* __restrict__ partial,
                                              const float* __restrict__ ew1,
                                              const float* __restrict__ ew2,
                                              short* __restrict__ W1T,
                                              short* __restrict__ W2T,
                                              const char* __restrict__ csrc1,
                                              const char* __restrict__ csrc2,
                                              char* __restrict__ bb,
                                              int ngemm) {
    __shared__ __align__(16) short lds[32768];
    int bid = blockIdx.x;
    int t = threadIdx.x;
    if (bid >= ngemm) {
        int i = bid - ngemm;
        if (MODE == 0) {
            if (i < 475) {
                size_t c = (size_t)(293 + i) * CHUNK;
                copy_chunk_raw(csrc1 + c, bb + c);
            } else if (i < 859) {
                size_t o = (size_t)(i - 475) * CHUNK;
                copy_chunk_raw(csrc2 + o, bb + S8DST + o);
            } else {
                int j = i - 859;  // 0..4607: expert weight converts
                int mat = j / 576, q = j % 576;
                int ci0 = (q % 24) * 32, co0 = (q / 24) * 32;
                const float* src = (mat < 4 ? ew1 : ew2) + (size_t)(mat & 3) * CCH * CCH;
                short* dst = (mat < 4 ? W1T : W2T) + (size_t)(mat & 3) * CCH * CCH;
                float* tile = (float*)lds;  // [32][33]
                int tx = t & 31, ty = t >> 5;
#pragma unroll
                for (int i4 = 0; i4 < 4; ++i4)
                    tile[(ty + 8 * i4) * 33 + tx] =
                        src[(size_t)(ci0 + ty + 8 * i4) * CCH + co0 + tx];
                __syncthreads();
#pragma unroll
                for (int i4 = 0; i4 < 4; ++i4) {
                    int co = co0 + ty + 8 * i4;
                    dst[(size_t)co * CCH + ci0 + tx] = f2b(tile[tx * 33 + ty + 8 * i4]);
                }
            }
        } else if (MODE == 1) {
            if (i < 57) {
                size_t c = (size_t)(170 + i) * CHUNK;
                copy_chunk_raw(csrc1 + c, bb + c);
            } else {
                size_t o = (size_t)(i - 57) * CHUNK;
                copy_chunk_raw(csrc2 + o, bb + S16DST + o);
            }
        } else {
            if (i < 66) {
                size_t c = (size_t)(227 + i) * CHUNK;
                copy_chunk_raw(csrc1 + c, bb + c);
            } else {
                size_t o = (size_t)(96 + i - 66) * CHUNK;
                copy_chunk_raw(csrc2 + (size_t)(i - 66) * CHUNK, bb + S16DST + o - (size_t)96 * CHUNK + (size_t)96 * CHUNK);
            }
        }
        return;
    }

    int cbk = bid % 6;
    int mt = bid / 6;
    int c0 = cbk * 128;
    int e = 0, ts = mt, cnt = 1 << 30, ofs = 0, mrow0 = 0;
    if (MODE == 0) {
        mrow0 = mt * 128;
    } else {
        e = mt >> 6;
        ts = mt & 63;
        int n0 = counts[0], n1 = counts[1], n2 = counts[2], n3 = counts[3];
        cnt = (e == 0) ? n0 : (e == 1) ? n1 : (e == 2) ? n2 : n3;
        if (ts * 128 >= cnt) return;
        ofs = (e > 0 ? n0 : 0) + (e > 1 ? n1 : 0) + (e > 2 ? n2 : 0);
    }

    int lane = t & 63, w = t >> 6;
    int wr = w >> 1, wc = w & 1;
    int lrow = lane & 15, lk8 = lane >> 4;

    const short* aS[4];
    const short* bS[4];
    const short* alS[2];
    const short* blS[2];
    int dA[4];

    if (MODE == 0) {
#pragma unroll
        for (int i = 0; i < 2; ++i) {
            int c = 2 * w + i;
            int row = c * 16 + lrow;
            int koff = lk8 * 8;
            aS[i]  = Ahp + (size_t)(mrow0 + row) * CCH + koff;
            alS[i] = Alp + (size_t)(mrow0 + row) * CCH + koff;
            bS[i]  = Bhp + (size_t)(c0 + row) * CCH + koff;
            blS[i] = Blp + (size_t)(c0 + row) * CCH + koff;
            dA[i] = c * 512;
        }
    } else {
        size_t eoff = (size_t)e * CCH * CCH;
#pragma unroll
        for (int i = 0; i < 4; ++i) {
            int c = 4 * w + i;
            int g = c >> 1, ph = c & 1;
            int row = g * 16 + lrow;
            int koff = ph * 32 + lk8 * 8;
            int pl = ts * 128 + row;
            int pc = pl < cnt ? pl : cnt - 1;
            int tokrow = (MODE == 1) ? perm[ofs + pc] : (ofs + pc);
            aS[i] = Ahp + (size_t)tokrow * CCH + koff;
            bS[i] = Bhp + eoff + (size_t)(c0 + row) * CCH + koff;
            dA[i] = c * 512;
        }
    }

    f32x4 acc[4][4] = {};

    if (MODE == 0) {
        auto stage = [&](int b, int k0) {
            short* L = lds + b * 16384;
#pragma unroll
            for (int i = 0; i < 2; ++i) {
                gl16(aS[i] + k0, L + dA[i]);
                gl16(bS[i] + k0, L + 4096 + dA[i]);
                gl16(alS[i] + k0, L + 8192 + dA[i]);
                gl16(blS[i] + k0, L + 12288 + dA[i]);
            }
        };
        stage(0, 0);
        __syncthreads();
        for (int tt = 0; tt < 24; ++tt) {
            int cur = tt & 1;
            if (tt < 23) stage(cur ^ 1, (tt + 1) * 32);
            const short* L = lds + cur * 16384;
            short8v af[4], bf[4], xf[4];
#pragma unroll
            for (int m = 0; m < 4; ++m)
                af[m] = *(const short8v*)(L + ((wr * 4 + m) * 64 + lane) * 8);
#pragma unroll
            for (int n = 0; n < 4; ++n)
                bf[n] = *(const short8v*)(L + 4096 + ((wc * 4 + n) * 64 + lane) * 8);
#pragma unroll
            for (int m = 0; m < 4; ++m)
#pragma unroll
                for (int n = 0; n < 4; ++n)
                    acc[m][n] = __builtin_amdgcn_mfma_f32_16x16x32_bf16(af[m], bf[n], acc[m][n], 0, 0, 0);
#pragma unroll
            for (int n = 0; n < 4; ++n)
                xf[n] = *(const short8v*)(L + 12288 + ((wc * 4 + n) * 64 + lane) * 8);
#pragma unroll
            for (int m = 0; m < 4; ++m)
#pragma unroll
                for (int n = 0; n < 4; ++n)
                    acc[m][n] = __builtin_amdgcn_mfma_f32_16x16x32_bf16(af[m], xf[n], acc[m][n], 0, 0, 0);
#pragma unroll
            for (int m = 0; m < 4; ++m)
                xf[m] = *(const short8v*)(L + 8192 + ((wr * 4 + m) * 64 + lane) * 8);
#pragma unroll
            for (int m = 0; m < 4; ++m)
#pragma unroll
                for (int n = 0; n < 4; ++n)
                    acc[m][n] = __builtin_amdgcn_mfma_f32_16x16x32_bf16(xf[m], bf[n], acc[m][n], 0, 0, 0);
            __syncthreads();
        }
    } else {
        auto stage = [&](int b, int k0) {
            short* L = lds + b * 16384;
#pragma unroll
            for (int i = 0; i < 4; ++i) {
                gl16(aS[i] + k0, L + dA[i]);
                gl16(bS[i] + k0, L + 8192 + dA[i]);
            }
        };
        stage(0, 0);
        __syncthreads();
        for (int tt = 0; tt < 12; ++tt) {
            int cur = tt & 1;
            if (tt < 11) stage(cur ^ 1, (tt + 1) * 64);
            const short* L = lds + cur * 16384;
#pragma unroll
            for (int kk = 0; kk < 2; ++kk) {
                short8v af[4], bf[4];
#pragma unroll
                for (int m = 0; m < 4; ++m)
                    af[m] = *(const short8v*)(L + (((wr * 4 + m) * 2 + kk) * 64 + lane) * 8);
#pragma unroll
                for (int n = 0; n < 4; ++n)
                    bf[n] = *(const short8v*)(L + 8192 + (((wc * 4 + n) * 2 + kk) * 64 + lane) * 8);
#pragma unroll
                for (int m = 0; m < 4; ++m)
#pragma unroll
                    for (int n = 0; n < 4; ++n)
                        acc[m][n] = __builtin_amdgcn_mfma_f32_16x16x32_bf16(af[m], bf[n], acc[m][n], 0, 0, 0);
            }
            __syncthreads();
        }
    }

    int cl = lane & 15, rh = (lane >> 4) * 4;
    if (MODE == 0) {
        int cb2 = cbk * 2 + wc;
        float bv[4];
        float4 w2v[4];
#pragma unroll
        for (int n_ = 0; n_ < 4; ++n_) {
            int col = c0 + wc * 64 + n_ * 16 + cl;
            bv[n_] = bias[col];
            w2v[n_] = *(const float4*)(gw2 + col * 4);
        }
#pragma unroll
        for (int m = 0; m < 4; ++m) {
#pragma unroll
            for (int ri = 0; ri < 4; ++ri) {
                float s0 = 0.f, s1 = 0.f, s2 = 0.f, s3 = 0.f;
#pragma unroll
                for (int n_ = 0; n_ < 4; ++n_) {
                    float g = gelu_tanh(acc[m][n_][ri] + bv[n_]);
                    s0 = fmaf(g, w2v[n_].x, s0);
                    s1 = fmaf(g, w2v[n_].y, s1);
                    s2 = fmaf(g, w2v[n_].z, s2);
                    s3 = fmaf(g, w2v[n_].w, s3);
                }
#pragma unroll
                for (int off = 1; off < 16; off <<= 1) {
                    s0 += __shfl_xor(s0, off);
                    s1 += __shfl_xor(s1, off);
                    s2 += __shfl_xor(s2, off);
                    s3 += __shfl_xor(s3, off);
                }
                if (cl == 0) {
                    int row = mrow0 + wr * 64 + m * 16 + rh + ri;
                    float4 pv;
                    pv.x = s0; pv.y = s1; pv.z = s2; pv.w = s3;
                    *(float4*)(partial + (size_t)(cb2 * 8192 + row) * 4) = pv;
                }
            }
        }
    } else {
#pragma unroll
        for (int n = 0; n < 4; ++n) {
            int col = c0 + wc * 64 + n * 16 + cl;
            float bv = bias[e * CCH + col];
#pragma unroll
            for (int m = 0; m < 4; ++m) {
#pragma unroll
                for (int ri = 0; ri < 4; ++ri) {
                    int p = ts * 128 + wr * 64 + m * 16 + rh + ri;
                    if (p < cnt) {
                        float v = acc[m][n][ri] + bv;
                        if (MODE == 1) {
                            Hout[(size_t)(ofs + p) * CCH + col] = f2b(gelu_tanh(v));
                        } else {
                            int nn = perm[ofs + p];
                            Yt[(size_t)nn * CCH + col] = v * gval[nn];
                        }
                    }
                }
            }
        }
    }
}

// sum 12 partial-logit slabs + b2 -> argmax / softmax top-1 / counts
__global__ __launch_bounds__(256) void k_route(const float* __restrict__ partial,
                                               const float* __restrict__ b2,
                                               int* __restrict__ idx,
                                               float* __restrict__ gval,
                                               int* __restrict__ counts) {
    int n = blockIdx.x * 256 + threadIdx.x;
    float l0 = b2[0], l1 = b2[1], l2 = b2[2], l3 = b2[3];
#pragma unroll
    for (int p = 0; p < 12; ++p) {
        float4 v = *(const float4*)(partial + ((size_t)p * 8192 + n) * 4);
        l0 += v.x; l1 += v.y; l2 += v.z; l3 += v.w;
    }
    int e = 0;
    float m = l0;
    if (l1 > m) { m = l1; e = 1; }
    if (l2 > m) { m = l2; e = 2; }
    if (l3 > m) { m = l3; e = 3; }
    float s = __expf(l0 - m) + __expf(l1 - m) + __expf(l2 - m) + __expf(l3 - m);
    idx[n] = e;
    gval[n] = 1.0f / s;
    atomicAdd(counts + e, 1);
}

// scatter with in-register prefix over the finalized counts
__global__ __launch_bounds__(256) void k_scatter(const int* __restrict__ idx,
                                                 const int* __restrict__ counts,
                                                 int* __restrict__ cursors,
                                                 int* __restrict__ perm) {
    int n = blockIdx.x * 256 + threadIdx.x;
    int e = idx[n];
    int run = 0;
#pragma unroll
    for (int ee = 0; ee < 4; ++ee) {
        int c = counts[ee];
        if (e == ee) {
            int pos = run + atomicAdd(cursors + ee, 1);
            perm[pos] = n;
        }
        run += c;
    }
}

// out32 = Yt (token-major) + s32, both sides coalesced
__global__ __launch_bounds__(256) void k_untr(const float* __restrict__ Yt,
                                              const float* __restrict__ s32,
                                              float* __restrict__ out32) {
    __shared__ float tile[32][33];
    int b = blockIdx.z;
    int c0 = blockIdx.y * 32, hw0 = blockIdx.x * 32;
    int tx = threadIdx.x, ty = threadIdx.y;
#pragma unroll
    for (int i = 0; i < 4; ++i) {
        int hwl = ty + 8 * i;
        tile[hwl][tx] = Yt[(size_t)(b * 1024 + hw0 + hwl) * CCH + c0 + tx];
    }
    __syncthreads();
    const float* sp = s32 + (size_t)b * CCH * 1024;
    float* op = out32 + (size_t)b * CCH * 1024;
#pragma unroll
    for (int i = 0; i < 4; ++i) {
        size_t a = (size_t)(c0 + ty + 8 * i) * 1024 + hw0 + tx;
        op[a] = tile[tx][ty + 8 * i] + sp[a];
    }
}

extern "C" void kernel_launch(void* const* d_in, const int* in_sizes, int n_in,
                              void* d_out, int out_size, void* d_ws, size_t ws_size,
                              hipStream_t stream) {
    const float* s4  = (const float*)d_in[0];
    const float* s8  = (const float*)d_in[1];
    const float* s16 = (const float*)d_in[2];
    const float* s32 = (const float*)d_in[3];
    const float* gw1 = (const float*)d_in[4];
    const float* gb1 = (const float*)d_in[5];
    const float* gw2 = (const float*)d_in[6];
    const float* gb2 = (const float*)d_in[7];
    const float* ew1 = (const float*)d_in[8];
    const float* eb1 = (const float*)d_in[9];
    const float* ew2 = (const float*)d_in[10];
    const float* eb2 = (const float*)d_in[11];

    char* bb = (char*)d_out;
    float* Yt      = (float*)(bb + OFF_YT);
    short* Hh      = (short*)(bb + OFF_HH);
    short* W2T     = (short*)(bb + OFF_W2T);
    int*   idx     = (int*)(bb + OFF_IDX);
    int*   perm    = (int*)(bb + OFF_PERM);
    int*   counts  = (int*)(bb + OFF_CNT);
    int*   cursors = (int*)(bb + OFF_CUR);
    float* gval    = (float*)(bb + OFF_GVAL);
    float* partial = (float*)(bb + OFF_PART);
    short* Xl      = (short*)(bb + OFF_XL);
    short* GWh     = (short*)(bb + OFF_GWH);
    short* GWl     = (short*)(bb + OFF_GWL);
    short* Xh      = (short*)(bb + OFF_XH);
    short* W1T     = (short*)(bb + OFF_W1T);
    float* out32   = (float*)(bb + OUTDST);

    k_prep<<<dim3(32, 24, 9), dim3(32, 8), 0, stream>>>(s32, gw1, Xh, Xl, GWh, GWl, counts);
    // gate (split-bf16 GEMM + fused logit partials) + early-s4/s8 copies + ew converts
    k_mfma<0><<<384 + 859 + 4608, 256, 0, stream>>>(Xh, Xl, GWh, GWl, gb1, gw2,
                                                    perm, counts, gval, Yt, Hh,
                                                    partial, ew1, ew2, W1T, W2T,
                                                    (const char*)s4, (const char*)s8,
                                                    bb, 384);
    k_route<<<32, 256, 0, stream>>>(partial, gb2, idx, gval, counts);
    k_scatter<<<32, 256, 0, stream>>>(idx, counts, cursors, perm);
    // expert layer 1 + mid1/s16-first-half copies
    k_mfma<1><<<1536 + 153, 256, 0, stream>>>(Xh, Xl, W1T, GWl, eb1, gw2,
                                              perm, counts, gval, Yt, Hh,
                                              partial, ew1, ew2, W1T, W2T,
                                              (const char*)s4, (const char*)s16,
                                              bb, 1536);
    // expert layer 2 + mid2/s16-second-half copies
    k_mfma<2><<<1536 + 162, 256, 0, stream>>>(Hh, Xl, W2T, GWl, eb2, gw2,
                                              perm, counts, gval, Yt, Hh,
                                              partial, ew1, ew2, W1T, W2T,
                                              (const char*)s4, (const char*)(s16 + (size_t)96 * CHUNK / 4),
                                              bb, 1536);
    k_untr<<<dim3(32, 24, 8), dim3(32, 8), 0, stream>>>(Yt, s32, out32);
    hipMemcpyAsync(bb, s4, (size_t)TAILBYTES, hipMemcpyDeviceToDevice, stream);
}